// Round 4
// baseline (11921.084 us; speedup 1.0000x reference)
//
#include <hip/hip_runtime.h>
#include <hip/hip_bf16.h>
#include <stdint.h>

#define N_ 256
#define T_ 128
#define D_ 1024
#define H_ 1024
#define FH_ 4096
#define K2_ 2048

typedef __bf16 bf16x8 __attribute__((ext_vector_type(8)));
typedef float f32x4 __attribute__((ext_vector_type(4)));

// ---------------- transpose + cast fp32 -> bf16 ----------------
__global__ __launch_bounds__(256) void transpose_cast(
    const float* __restrict__ src, int cols,
    __hip_bfloat16* __restrict__ dst, int dst_stride, int dst_coloff)
{
    __shared__ float tile[32][33];
    int cb = blockIdx.x * 32, rb = blockIdx.y * 32;
    int tx = threadIdx.x, ty = threadIdx.y;  // (32, 8)
#pragma unroll
    for (int i = 0; i < 4; i++)
        tile[ty + i * 8][tx] = src[(size_t)(rb + ty + i * 8) * cols + cb + tx];
    __syncthreads();
#pragma unroll
    for (int i = 0; i < 4; i++)
        dst[(size_t)(cb + ty + i * 8) * dst_stride + dst_coloff + rb + tx] =
            __float2bfloat16(tile[tx][ty + i * 8]);
}

// ---------------- xproj GEMM: C[g][j] = sum_k x[g][k] * WxT[j][k] ----------
// row g -> (n = g&255, t = t0 + (g>>8)).  OUTBF: 1 = bf16 output, 0 = fp32.
#define BM 64
#define BN 128
#define BK 64
#define BKP 72

template <int OUTBF>
__global__ __launch_bounds__(256) void gemm_x(
    const float* __restrict__ Xf,
    const __hip_bfloat16* __restrict__ BT,
    void* __restrict__ Cp, int t0)
{
    __shared__ __hip_bfloat16 Al[BM][BKP];
    __shared__ __hip_bfloat16 Bl[BN][BKP];
    const int tid = threadIdx.x;
    const int lane = tid & 63, wid = tid >> 6;
    const int m0 = blockIdx.y * BM, n0 = blockIdx.x * BN;
    const int wm = (wid >> 1) * 32, wn = (wid & 1) * 64;
    const int rs = tid >> 3, kc = (tid & 7) * 8;
    f32x4 acc[2][4] = {};

    for (int k0 = 0; k0 < D_; k0 += BK) {
#pragma unroll
        for (int p = 0; p < BM; p += 32) {
            int r = rs + p;
            int g = m0 + r;
            int nn = g & 255, tl = g >> 8;
            const float* s = Xf + ((size_t)nn * T_ + (t0 + tl)) * D_ + k0 + kc;
            float4 v0 = *reinterpret_cast<const float4*>(s);
            float4 v1 = *reinterpret_cast<const float4*>(s + 4);
            __hip_bfloat16 h8[8];
            h8[0] = __float2bfloat16(v0.x); h8[1] = __float2bfloat16(v0.y);
            h8[2] = __float2bfloat16(v0.z); h8[3] = __float2bfloat16(v0.w);
            h8[4] = __float2bfloat16(v1.x); h8[5] = __float2bfloat16(v1.y);
            h8[6] = __float2bfloat16(v1.z); h8[7] = __float2bfloat16(v1.w);
            *reinterpret_cast<int4*>(&Al[r][kc]) = *reinterpret_cast<const int4*>(h8);
        }
#pragma unroll
        for (int p = 0; p < BN; p += 32) {
            int r = rs + p;
            const __hip_bfloat16* s = BT + (size_t)(n0 + r) * D_ + k0 + kc;
            *reinterpret_cast<int4*>(&Bl[r][kc]) = *reinterpret_cast<const int4*>(s);
        }
        __syncthreads();
        const int ko = (lane >> 4) * 8;
#pragma unroll
        for (int kk = 0; kk < BK; kk += 32) {
            bf16x8 a0 = *reinterpret_cast<const bf16x8*>(&Al[wm + (lane & 15)][kk + ko]);
            bf16x8 a1 = *reinterpret_cast<const bf16x8*>(&Al[wm + 16 + (lane & 15)][kk + ko]);
#pragma unroll
            for (int ni = 0; ni < 4; ni++) {
                bf16x8 bq = *reinterpret_cast<const bf16x8*>(&Bl[wn + ni * 16 + (lane & 15)][kk + ko]);
                acc[0][ni] = __builtin_amdgcn_mfma_f32_16x16x32_bf16(a0, bq, acc[0][ni], 0, 0, 0);
                acc[1][ni] = __builtin_amdgcn_mfma_f32_16x16x32_bf16(a1, bq, acc[1][ni], 0, 0, 0);
            }
        }
        __syncthreads();
    }
    const int cr = (lane >> 4) * 4, ccol = lane & 15;
#pragma unroll
    for (int mi = 0; mi < 2; mi++)
#pragma unroll
        for (int ni = 0; ni < 4; ni++)
#pragma unroll
            for (int r = 0; r < 4; r++) {
                size_t idx = (size_t)(m0 + wm + mi * 16 + cr + r) * FH_ + (n0 + wn + ni * 16 + ccol);
                if constexpr (OUTBF) {
                    ((__hip_bfloat16*)Cp)[idx] = __float2bfloat16(acc[mi][ni][r]);
                } else {
                    ((float*)Cp)[idx] = acc[mi][ni][r];
                }
            }
}

// ---------------- init for persistent path ----------------
// h0, c0, hb0 h-half, sp partials; block 0 zeros the barrier counters.
__global__ __launch_bounds__(256) void init_pers(
    const float* __restrict__ Afp, float* __restrict__ cbuf,
    __hip_bfloat16* __restrict__ hb0, float* __restrict__ sp_part,
    unsigned* __restrict__ bar)
{
    const int n = blockIdx.x, tid = threadIdx.x;
    if (n == 0) { bar[tid] = 0u; bar[256 + tid] = 0u; }
    float a[4][16];
    float hv[4];
#pragma unroll
    for (int q = 0; q < 4; q++) {
        const float4* Ap = reinterpret_cast<const float4*>(Afp + ((size_t)n * H_ + tid * 4 + q) * 16);
        float4 q0 = Ap[0], q1 = Ap[1], q2 = Ap[2], q3 = Ap[3];
        a[q][0] = q0.x; a[q][1] = q0.y; a[q][2] = q0.z; a[q][3] = q0.w;
        a[q][4] = q1.x; a[q][5] = q1.y; a[q][6] = q1.z; a[q][7] = q1.w;
        a[q][8] = q2.x; a[q][9] = q2.y; a[q][10] = q2.z; a[q][11] = q2.w;
        a[q][12] = q3.x; a[q][13] = q3.y; a[q][14] = q3.z; a[q][15] = q3.w;
        float s = 0.f;
#pragma unroll
        for (int l = 0; l < 16; l++) s += a[q][l];
        hv[q] = s * 0.0625f;
    }
    *reinterpret_cast<float4*>(cbuf + (size_t)n * H_ + tid * 4) = *reinterpret_cast<float4*>(hv);
    __hip_bfloat16 h4[4];
#pragma unroll
    for (int q = 0; q < 4; q++) h4[q] = __float2bfloat16(hv[q]);
    *reinterpret_cast<uint2*>(hb0 + (size_t)n * K2_ + tid * 4) = *reinterpret_cast<uint2*>(h4);
    float spv[16];
#pragma unroll
    for (int l = 0; l < 16; l++)
        spv[l] = hv[0] * a[0][l] + hv[1] * a[1][l] + hv[2] * a[2][l] + hv[3] * a[3][l];
#pragma unroll
    for (int l = 0; l < 16; l++) spv[l] += __shfl_xor(spv[l], 1);
    if ((tid & 1) == 0) {
        float* d = sp_part + (size_t)n * 2048 + (tid >> 1) * 16;
        *reinterpret_cast<float4*>(d)      = *reinterpret_cast<float4*>(&spv[0]);
        *reinterpret_cast<float4*>(d + 4)  = *reinterpret_cast<float4*>(&spv[4]);
        *reinterpret_cast<float4*>(d + 8)  = *reinterpret_cast<float4*>(&spv[8]);
        *reinterpret_cast<float4*>(d + 12) = *reinterpret_cast<float4*>(&spv[12]);
    }
}

// ---------------- 2-level grid barrier (256 WGs, 8 leaves x 32) -----------
// bar layout (uints): leaf[i] at i*32 (i=0..7), root at 8*32, gen at 8*32+32.
__device__ __forceinline__ void gridbar(unsigned* bar, int g)
{
    __syncthreads();
    if (threadIdx.x == 0) {
        __threadfence();
        unsigned* leaf = bar + (g & 7) * 32;
        unsigned* root = bar + 8 * 32;
        unsigned* gen  = bar + 8 * 32 + 32;
        unsigned tl = __hip_atomic_fetch_add(leaf, 1u, __ATOMIC_ACQ_REL, __HIP_MEMORY_SCOPE_AGENT);
        unsigned r = tl >> 5;
        if ((tl & 31u) == 31u) {
            unsigned tr = __hip_atomic_fetch_add(root, 1u, __ATOMIC_ACQ_REL, __HIP_MEMORY_SCOPE_AGENT);
            if ((tr & 7u) == 7u)
                __hip_atomic_store(gen, r + 1u, __ATOMIC_RELEASE, __HIP_MEMORY_SCOPE_AGENT);
        }
        while (__hip_atomic_load(gen, __ATOMIC_ACQUIRE, __HIP_MEMORY_SCOPE_AGENT) < r + 1u)
            __builtin_amdgcn_s_sleep(1);
        __threadfence();
    }
    __syncthreads();
}

// ---------------- persistent all-timesteps kernel ----------------
// 256 WGs x 256 thr. WG g: jt = g&127 (8 hidden cols), mt = g>>7 (128 n rows).
// W2 slice (32 rows x 2048) LDS-resident for all 128 steps.
__global__ __launch_bounds__(256, 1) void persist(
    const __hip_bfloat16* __restrict__ W2T,
    __hip_bfloat16* __restrict__ hbA,
    __hip_bfloat16* __restrict__ hbB,
    const __hip_bfloat16* __restrict__ xpb,
    const float* __restrict__ bias,
    const float* __restrict__ Afp,
    const float* __restrict__ cinit,
    float* __restrict__ sp_part,
    float* __restrict__ out,
    unsigned* __restrict__ bar)
{
    __shared__ __align__(16) char smem[149056];
    float* pls  = (float*)(smem + 131072);   // [128][33]
    float* redA = (float*)(smem + 147968);   // [16][16] + w[16]

    const int tid = threadIdx.x;
    const int g = blockIdx.x;
    const int jt = g & 127, mt = g >> 7;
    const int hc0 = jt * 8, n0 = mt * 128;
    const int lane = tid & 63, wv = tid >> 6;
    const int l15 = lane & 15, ko = (lane >> 4) * 8;

    // ---- load W2 slice into LDS (rows j_l = s*8+c -> global s*1024+hc0+c) ----
    {
        const int jl = tid >> 3;            // 0..31
        const int s = jl >> 3, c = jl & 7;
        const int kc = (tid & 7) * 8;
        const __hip_bfloat16* src = W2T + ((size_t)(s * 1024 + hc0 + c)) * K2_ + kc;
        const int swz = (jl & 7) << 4;
        for (int q = 0; q < 32; q++) {
            int k = kc + q * 64;
            int4 v = *reinterpret_cast<const int4*>(src + q * 64);
            *reinterpret_cast<int4*>(smem + jl * 4096 + ((k * 2) ^ swz)) = v;
        }
    }

    // epilogue-constant state
    const int n_l = tid >> 1, hcq = (tid & 1) * 4;
    const int nn = n0 + n_l;
    float cv[4];
    *reinterpret_cast<float4*>(cv) =
        *reinterpret_cast<const float4*>(cinit + (size_t)nn * H_ + hc0 + hcq);
    float bv[4][4];
#pragma unroll
    for (int s = 0; s < 4; s++)
        *reinterpret_cast<float4*>(bv[s]) =
            *reinterpret_cast<const float4*>(bias + s * 1024 + hc0 + hcq);

    // per-lane swizzled LDS bases for B-frags (valid: low parts < 128, k0*2 mult 128)
    const int swzb = (l15 & 7) << 4;
    const int wb00 = l15 * 4096 + ((ko * 2) ^ swzb);
    const int wb01 = l15 * 4096 + (((64 + ko * 2)) ^ swzb);
    const int wb10 = (16 + l15) * 4096 + ((ko * 2) ^ swzb);
    const int wb11 = (16 + l15) * 4096 + (((64 + ko * 2)) ^ swzb);

    __syncthreads();

    for (int t = 0; t < T_; ++t) {
        const __hip_bfloat16* hbin = (t & 1) ? hbB : hbA;
        __hip_bfloat16* hbatt      = (t & 1) ? hbB : hbA;
        __hip_bfloat16* hbout      = (t & 1) ? hbA : hbB;

        // ---- phase A: softmax weights + attn for n = g ----
        {
            const int la = tid & 15, grp = tid >> 4;
            const float* sp = sp_part + (size_t)g * 2048;
            float s = 0.f;
#pragma unroll
            for (int j = 0; j < 8; j++) s += sp[(grp * 8 + j) * 16 + la];
            redA[grp * 16 + la] = s;
            __syncthreads();
            if (tid < 16) {
                float sc = 0.f;
#pragma unroll
                for (int q = 0; q < 16; q++) sc += redA[q * 16 + tid];
                sc *= 0.03125f;  // 1/sqrt(1024)
                float m = sc;
                m = fmaxf(m, __shfl_xor(m, 8)); m = fmaxf(m, __shfl_xor(m, 4));
                m = fmaxf(m, __shfl_xor(m, 2)); m = fmaxf(m, __shfl_xor(m, 1));
                float e = __expf(sc - m);
                float se = e;
                se += __shfl_xor(se, 8); se += __shfl_xor(se, 4);
                se += __shfl_xor(se, 2); se += __shfl_xor(se, 1);
                redA[256 + tid] = e / se;
            }
            __syncthreads();
            float w[16];
#pragma unroll
            for (int l = 0; l < 16; l++) w[l] = redA[256 + l];
            const float* Ar = Afp + ((size_t)g * H_ + tid * 4) * 16;
            __hip_bfloat16 at4[4];
#pragma unroll
            for (int q = 0; q < 4; q++) {
                float4 a0 = *reinterpret_cast<const float4*>(Ar + q * 16);
                float4 a1 = *reinterpret_cast<const float4*>(Ar + q * 16 + 4);
                float4 a2 = *reinterpret_cast<const float4*>(Ar + q * 16 + 8);
                float4 a3 = *reinterpret_cast<const float4*>(Ar + q * 16 + 12);
                float s2 = w[0]*a0.x + w[1]*a0.y + w[2]*a0.z + w[3]*a0.w
                         + w[4]*a1.x + w[5]*a1.y + w[6]*a1.z + w[7]*a1.w
                         + w[8]*a2.x + w[9]*a2.y + w[10]*a2.z + w[11]*a2.w
                         + w[12]*a3.x + w[13]*a3.y + w[14]*a3.z + w[15]*a3.w;
                at4[q] = __float2bfloat16(s2);
            }
            *reinterpret_cast<uint2*>(hbatt + (size_t)g * K2_ + H_ + tid * 4) =
                *reinterpret_cast<uint2*>(at4);
        }
        gridbar(bar, g);

        // ---- GEMM: K=2048, A global->regs, B LDS-resident ----
        f32x4 acc00{}, acc01{}, acc10{}, acc11{};
        const __hip_bfloat16* aB0 = hbin + (size_t)(n0 + wv * 32 + l15) * K2_ + ko;
        const __hip_bfloat16* aB1 = aB0 + 16 * K2_;
#pragma unroll
        for (int it = 0; it < 32; ++it) {
            const int k0 = it * 64;
            bf16x8 a00 = *reinterpret_cast<const bf16x8*>(aB0 + k0);
            bf16x8 a01 = *reinterpret_cast<const bf16x8*>(aB0 + k0 + 32);
            bf16x8 a10 = *reinterpret_cast<const bf16x8*>(aB1 + k0);
            bf16x8 a11 = *reinterpret_cast<const bf16x8*>(aB1 + k0 + 32);
            bf16x8 b00 = *reinterpret_cast<const bf16x8*>(smem + wb00 + k0 * 2);
            bf16x8 b10 = *reinterpret_cast<const bf16x8*>(smem + wb10 + k0 * 2);
            bf16x8 b01 = *reinterpret_cast<const bf16x8*>(smem + wb01 + k0 * 2);
            bf16x8 b11 = *reinterpret_cast<const bf16x8*>(smem + wb11 + k0 * 2);
            acc00 = __builtin_amdgcn_mfma_f32_16x16x32_bf16(a00, b00, acc00, 0, 0, 0);
            acc01 = __builtin_amdgcn_mfma_f32_16x16x32_bf16(a00, b10, acc01, 0, 0, 0);
            acc10 = __builtin_amdgcn_mfma_f32_16x16x32_bf16(a10, b00, acc10, 0, 0, 0);
            acc11 = __builtin_amdgcn_mfma_f32_16x16x32_bf16(a10, b10, acc11, 0, 0, 0);
            acc00 = __builtin_amdgcn_mfma_f32_16x16x32_bf16(a01, b01, acc00, 0, 0, 0);
            acc01 = __builtin_amdgcn_mfma_f32_16x16x32_bf16(a01, b11, acc01, 0, 0, 0);
            acc10 = __builtin_amdgcn_mfma_f32_16x16x32_bf16(a11, b01, acc10, 0, 0, 0);
            acc11 = __builtin_amdgcn_mfma_f32_16x16x32_bf16(a11, b11, acc11, 0, 0, 0);
        }
        {
            const int cr = (lane >> 4) * 4;
#pragma unroll
            for (int r = 0; r < 4; r++) {
                pls[(wv * 32 + cr + r) * 33 + l15]           = acc00[r];
                pls[(wv * 32 + cr + r) * 33 + 16 + l15]      = acc01[r];
                pls[(wv * 32 + 16 + cr + r) * 33 + l15]      = acc10[r];
                pls[(wv * 32 + 16 + cr + r) * 33 + 16 + l15] = acc11[r];
            }
        }
        __syncthreads();

        // ---- epilogue: gates, c (regs), h, out, score partials ----
        {
            const __hip_bfloat16* xrow = xpb + ((size_t)t * N_ + nn) * FH_ + hc0 + hcq;
            float pre[4][4];
#pragma unroll
            for (int s = 0; s < 4; s++) {
                __hip_bfloat16 xb[4];
                *reinterpret_cast<uint2*>(xb) = *reinterpret_cast<const uint2*>(xrow + s * 1024);
#pragma unroll
                for (int q = 0; q < 4; q++)
                    pre[s][q] = pls[n_l * 33 + s * 8 + hcq + q] + __bfloat162float(xb[q]) + bv[s][q];
            }
            float hq[4];
#pragma unroll
            for (int q = 0; q < 4; q++) {
                float iv = 1.f / (1.f + __expf(-pre[0][q]));
                float fv = 1.f / (1.f + __expf(-pre[1][q]));
                float ov = 1.f / (1.f + __expf(-pre[2][q]));
                float gx = fminf(fmaxf(pre[3][q], -20.f), 20.f);
                float eg = __expf(2.f * gx);
                float gv = (eg - 1.f) / (eg + 1.f);
                float c2 = fv * cv[q] + iv * gv;
                cv[q] = c2;
                float cx = fminf(fmaxf(c2, -20.f), 20.f);
                float ec = __expf(2.f * cx);
                hq[q] = ov * (ec - 1.f) / (ec + 1.f);
            }
            *reinterpret_cast<float4*>(out + ((size_t)nn * T_ + t) * H_ + hc0 + hcq) =
                *reinterpret_cast<float4*>(hq);
            __hip_bfloat16 h4[4];
#pragma unroll
            for (int q = 0; q < 4; q++) h4[q] = __float2bfloat16(hq[q]);
            *reinterpret_cast<uint2*>(hbout + (size_t)nn * K2_ + hc0 + hcq) =
                *reinterpret_cast<uint2*>(h4);

            float spv[16];
#pragma unroll
            for (int l = 0; l < 16; l++) spv[l] = 0.f;
#pragma unroll
            for (int q = 0; q < 4; q++) {
                const float* ar = Afp + ((size_t)nn * H_ + hc0 + hcq + q) * 16;
                float4 a0 = *reinterpret_cast<const float4*>(ar);
                float4 a1 = *reinterpret_cast<const float4*>(ar + 4);
                float4 a2 = *reinterpret_cast<const float4*>(ar + 8);
                float4 a3 = *reinterpret_cast<const float4*>(ar + 12);
                float h = hq[q];
                spv[0] += h*a0.x;  spv[1] += h*a0.y;  spv[2] += h*a0.z;  spv[3] += h*a0.w;
                spv[4] += h*a1.x;  spv[5] += h*a1.y;  spv[6] += h*a1.z;  spv[7] += h*a1.w;
                spv[8] += h*a2.x;  spv[9] += h*a2.y;  spv[10] += h*a2.z; spv[11] += h*a2.w;
                spv[12] += h*a3.x; spv[13] += h*a3.y; spv[14] += h*a3.z; spv[15] += h*a3.w;
            }
#pragma unroll
            for (int l = 0; l < 16; l++) spv[l] += __shfl_xor(spv[l], 1);
            if ((tid & 1) == 0) {
                float* d = sp_part + (size_t)nn * 2048 + jt * 16;
                *reinterpret_cast<float4*>(d)      = *reinterpret_cast<float4*>(&spv[0]);
                *reinterpret_cast<float4*>(d + 4)  = *reinterpret_cast<float4*>(&spv[4]);
                *reinterpret_cast<float4*>(d + 8)  = *reinterpret_cast<float4*>(&spv[8]);
                *reinterpret_cast<float4*>(d + 12) = *reinterpret_cast<float4*>(&spv[12]);
            }
        }
        gridbar(bar, g);
    }
}

// ================= fallback (round-3) kernels =================
__global__ __launch_bounds__(256) void init_fb(
    const float* __restrict__ A, float* __restrict__ cbuf,
    __hip_bfloat16* __restrict__ hb)
{
    __shared__ float red[4][16];
    __shared__ float wl[16];
    const int n = blockIdx.x, tid = threadIdx.x;
    const int lane = tid & 63, wv = tid >> 6;
    const int h0i = tid * 4;
    float a[4][16];
    float hv[4];
#pragma unroll
    for (int q = 0; q < 4; q++) {
        const float4* Ap = reinterpret_cast<const float4*>(A + ((size_t)n * H_ + h0i + q) * 16);
        float4 q0 = Ap[0], q1 = Ap[1], q2 = Ap[2], q3 = Ap[3];
        a[q][0] = q0.x; a[q][1] = q0.y; a[q][2] = q0.z; a[q][3] = q0.w;
        a[q][4] = q1.x; a[q][5] = q1.y; a[q][6] = q1.z; a[q][7] = q1.w;
        a[q][8] = q2.x; a[q][9] = q2.y; a[q][10] = q2.z; a[q][11] = q2.w;
        a[q][12] = q3.x; a[q][13] = q3.y; a[q][14] = q3.z; a[q][15] = q3.w;
        float s = 0.f;
#pragma unroll
        for (int l = 0; l < 16; l++) s += a[q][l];
        hv[q] = s * 0.0625f;
    }
    *reinterpret_cast<float4*>(cbuf + (size_t)n * H_ + h0i) = *reinterpret_cast<float4*>(hv);
    {
        __hip_bfloat16 h4[4];
#pragma unroll
        for (int q = 0; q < 4; q++) h4[q] = __float2bfloat16(hv[q]);
        *reinterpret_cast<uint2*>(hb + (size_t)n * K2_ + h0i) = *reinterpret_cast<uint2*>(h4);
    }
    float sp[16];
#pragma unroll
    for (int l = 0; l < 16; l++) {
        sp[l] = hv[0] * a[0][l] + hv[1] * a[1][l] + hv[2] * a[2][l] + hv[3] * a[3][l];
#pragma unroll
        for (int off = 1; off < 64; off <<= 1) sp[l] += __shfl_xor(sp[l], off);
    }
    if (lane == 0) {
#pragma unroll
        for (int l = 0; l < 16; l++) red[wv][l] = sp[l];
    }
    __syncthreads();
    if (tid < 16) {
        float s = (red[0][tid] + red[1][tid] + red[2][tid] + red[3][tid]) * 0.03125f;
        float m = s;
        m = fmaxf(m, __shfl_xor(m, 8)); m = fmaxf(m, __shfl_xor(m, 4));
        m = fmaxf(m, __shfl_xor(m, 2)); m = fmaxf(m, __shfl_xor(m, 1));
        float e = __expf(s - m);
        float se = e;
        se += __shfl_xor(se, 8); se += __shfl_xor(se, 4);
        se += __shfl_xor(se, 2); se += __shfl_xor(se, 1);
        wl[tid] = e / se;
    }
    __syncthreads();
    float w[16];
#pragma unroll
    for (int l = 0; l < 16; l++) w[l] = wl[l];
    __hip_bfloat16 at4[4];
#pragma unroll
    for (int q = 0; q < 4; q++) {
        float s = 0.f;
#pragma unroll
        for (int l = 0; l < 16; l++) s += w[l] * a[q][l];
        at4[q] = __float2bfloat16(s);
    }
    *reinterpret_cast<uint2*>(hb + (size_t)n * K2_ + H_ + h0i) = *reinterpret_cast<uint2*>(at4);
}

__global__ __launch_bounds__(256) void wattn(
    const float* __restrict__ sp_part, const float* __restrict__ A,
    __hip_bfloat16* __restrict__ hb)
{
    __shared__ float red[4][16];
    __shared__ float wl[16];
    const int n = blockIdx.x, tid = threadIdx.x;
    if (tid < 64) {
        const int g = tid >> 4, l = tid & 15;
        float s = 0.f;
        const float* sp = sp_part + ((size_t)n * 64 + g * 16) * 16 + l;
#pragma unroll
        for (int j = 0; j < 16; j++) s += sp[j * 16];
        red[g][l] = s;
    }
    __syncthreads();
    if (tid < 16) {
        float s = (red[0][tid] + red[1][tid] + red[2][tid] + red[3][tid]) * 0.03125f;
        float m = s;
        m = fmaxf(m, __shfl_xor(m, 8)); m = fmaxf(m, __shfl_xor(m, 4));
        m = fmaxf(m, __shfl_xor(m, 2)); m = fmaxf(m, __shfl_xor(m, 1));
        float e = __expf(s - m);
        float se = e;
        se += __shfl_xor(se, 8); se += __shfl_xor(se, 4);
        se += __shfl_xor(se, 2); se += __shfl_xor(se, 1);
        wl[tid] = e / se;
    }
    __syncthreads();
    float w[16];
#pragma unroll
    for (int l = 0; l < 16; l++) w[l] = wl[l];
    const int h0i = tid * 4;
    __hip_bfloat16 at4[4];
#pragma unroll
    for (int q = 0; q < 4; q++) {
        const float4* Ap = reinterpret_cast<const float4*>(A + ((size_t)n * H_ + h0i + q) * 16);
        float4 q0 = Ap[0], q1 = Ap[1], q2 = Ap[2], q3 = Ap[3];
        float s = w[0] * q0.x + w[1] * q0.y + w[2] * q0.z + w[3] * q0.w
                + w[4] * q1.x + w[5] * q1.y + w[6] * q1.z + w[7] * q1.w
                + w[8] * q2.x + w[9] * q2.y + w[10] * q2.z + w[11] * q2.w
                + w[12] * q3.x + w[13] * q3.y + w[14] * q3.z + w[15] * q3.w;
        at4[q] = __float2bfloat16(s);
    }
    *reinterpret_cast<uint2*>(hb + (size_t)n * K2_ + H_ + h0i) = *reinterpret_cast<uint2*>(at4);
}

__global__ __launch_bounds__(256) void gemmgates(
    const __hip_bfloat16* __restrict__ hb_in,
    __hip_bfloat16* __restrict__ hb_out,
    const __hip_bfloat16* __restrict__ W2T,
    const float* __restrict__ xp,
    const float* __restrict__ bias,
    const float* __restrict__ Afp,
    float* __restrict__ cbuf,
    float* __restrict__ sp_part,
    float* __restrict__ out, int t)
{
    __shared__ __hip_bfloat16 Al[64][72];
    __shared__ __hip_bfloat16 Bl[64][72];
    __shared__ float pls[64][68];
    const int tid = threadIdx.x;
    const int lane = tid & 63, wv = tid >> 6;
    const int jt = blockIdx.x, mt = blockIdx.y;
    const int hc0 = jt * 16, n0 = mt * 64;
    const int rs = tid >> 3, kc = (tid & 7) * 8;
    const int wm = (wv >> 1) * 32, wn = (wv & 1) * 32;
    f32x4 acc[2][2] = {};

    for (int k0 = 0; k0 < K2_; k0 += 64) {
#pragma unroll
        for (int p = 0; p < 64; p += 32) {
            int r = rs + p;
            *reinterpret_cast<int4*>(&Al[r][kc]) =
                *reinterpret_cast<const int4*>(hb_in + (size_t)(n0 + r) * K2_ + k0 + kc);
            int grow = (r >> 4) * 1024 + hc0 + (r & 15);
            *reinterpret_cast<int4*>(&Bl[r][kc]) =
                *reinterpret_cast<const int4*>(W2T + (size_t)grow * K2_ + k0 + kc);
        }
        __syncthreads();
        const int ko = (lane >> 4) * 8;
#pragma unroll
        for (int kk = 0; kk < 64; kk += 32) {
            bf16x8 a0 = *reinterpret_cast<const bf16x8*>(&Al[wm + (lane & 15)][kk + ko]);
            bf16x8 a1 = *reinterpret_cast<const bf16x8*>(&Al[wm + 16 + (lane & 15)][kk + ko]);
            bf16x8 b0 = *reinterpret_cast<const bf16x8*>(&Bl[wn + (lane & 15)][kk + ko]);
            bf16x8 b1 = *reinterpret_cast<const bf16x8*>(&Bl[wn + 16 + (lane & 15)][kk + ko]);
            acc[0][0] = __builtin_amdgcn_mfma_f32_16x16x32_bf16(a0, b0, acc[0][0], 0, 0, 0);
            acc[0][1] = __builtin_amdgcn_mfma_f32_16x16x32_bf16(a0, b1, acc[0][1], 0, 0, 0);
            acc[1][0] = __builtin_amdgcn_mfma_f32_16x16x32_bf16(a1, b0, acc[1][0], 0, 0, 0);
            acc[1][1] = __builtin_amdgcn_mfma_f32_16x16x32_bf16(a1, b1, acc[1][1], 0, 0, 0);
        }
        __syncthreads();
    }
    {
        const int cr = (lane >> 4) * 4, cc = lane & 15;
#pragma unroll
        for (int mf = 0; mf < 2; mf++)
#pragma unroll
            for (int nf = 0; nf < 2; nf++)
#pragma unroll
                for (int r = 0; r < 4; r++)
                    pls[wm + mf * 16 + cr + r][wn + nf * 16 + cc] = acc[mf][nf][r];
    }
    __syncthreads();
    {
        const int n_l = tid >> 2, hcq = (tid & 3) * 4;
        const int nn = n0 + n_l;
        float pre_[4][4];
#pragma unroll
        for (int s = 0; s < 4; s++) {
            const int gj = s * 1024 + hc0 + hcq;
            float4 xv = *reinterpret_cast<const float4*>(xp + (size_t)nn * FH_ + gj);
            float4 bvv = *reinterpret_cast<const float4*>(bias + gj);
            float4 pv = *reinterpret_cast<const float4*>(&pls[n_l][s * 16 + hcq]);
            pre_[s][0] = pv.x + xv.x + bvv.x;
            pre_[s][1] = pv.y + xv.y + bvv.y;
            pre_[s][2] = pv.z + xv.z + bvv.z;
            pre_[s][3] = pv.w + xv.w + bvv.w;
        }
        float cvv[4];
        *reinterpret_cast<float4*>(cvv) =
            *reinterpret_cast<const float4*>(cbuf + (size_t)nn * H_ + hc0 + hcq);
        float hq[4];
#pragma unroll
        for (int q = 0; q < 4; q++) {
            float iv = 1.f / (1.f + __expf(-pre_[0][q]));
            float fv = 1.f / (1.f + __expf(-pre_[1][q]));
            float ov = 1.f / (1.f + __expf(-pre_[2][q]));
            float gx = fminf(fmaxf(pre_[3][q], -20.f), 20.f);
            float eg = __expf(2.f * gx);
            float gv = (eg - 1.f) / (eg + 1.f);
            float cc2 = fv * cvv[q] + iv * gv;
            cvv[q] = cc2;
            float cx = fminf(fmaxf(cc2, -20.f), 20.f);
            float ec = __expf(2.f * cx);
            hq[q] = ov * (ec - 1.f) / (ec + 1.f);
        }
        *reinterpret_cast<float4*>(cbuf + (size_t)nn * H_ + hc0 + hcq) =
            *reinterpret_cast<float4*>(cvv);
        *reinterpret_cast<float4*>(out + ((size_t)nn * T_ + t) * H_ + hc0 + hcq) =
            *reinterpret_cast<float4*>(hq);
        __hip_bfloat16 h4[4];
#pragma unroll
        for (int q = 0; q < 4; q++) h4[q] = __float2bfloat16(hq[q]);
        *reinterpret_cast<uint2*>(hb_out + (size_t)nn * K2_ + hc0 + hcq) =
            *reinterpret_cast<uint2*>(h4);

        float spv[16];
#pragma unroll
        for (int l = 0; l < 16; l++) spv[l] = 0.f;
#pragma unroll
        for (int q = 0; q < 4; q++) {
            const float* ar = Afp + ((size_t)nn * H_ + hc0 + hcq + q) * 16;
            float4 a0 = *reinterpret_cast<const float4*>(ar);
            float4 a1 = *reinterpret_cast<const float4*>(ar + 4);
            float4 a2 = *reinterpret_cast<const float4*>(ar + 8);
            float4 a3 = *reinterpret_cast<const float4*>(ar + 12);
            spv[0] += hq[q] * a0.x; spv[1] += hq[q] * a0.y;
            spv[2] += hq[q] * a0.z; spv[3] += hq[q] * a0.w;
            spv[4] += hq[q] * a1.x; spv[5] += hq[q] * a1.y;
            spv[6] += hq[q] * a1.z; spv[7] += hq[q] * a1.w;
            spv[8] += hq[q] * a2.x; spv[9] += hq[q] * a2.y;
            spv[10] += hq[q] * a2.z; spv[11] += hq[q] * a2.w;
            spv[12] += hq[q] * a3.x; spv[13] += hq[q] * a3.y;
            spv[14] += hq[q] * a3.z; spv[15] += hq[q] * a3.w;
        }
#pragma unroll
        for (int l = 0; l < 16; l++) {
            spv[l] += __shfl_xor(spv[l], 1);
            spv[l] += __shfl_xor(spv[l], 2);
        }
        if ((tid & 3) == 0) {
            float* d = sp_part + ((size_t)nn * 64 + jt) * 16;
            *reinterpret_cast<float4*>(d)      = *reinterpret_cast<float4*>(&spv[0]);
            *reinterpret_cast<float4*>(d + 4)  = *reinterpret_cast<float4*>(&spv[4]);
            *reinterpret_cast<float4*>(d + 8)  = *reinterpret_cast<float4*>(&spv[8]);
            *reinterpret_cast<float4*>(d + 12) = *reinterpret_cast<float4*>(&spv[12]);
        }
    }
}

extern "C" void kernel_launch(void* const* d_in, const int* in_sizes, int n_in,
                              void* d_out, int out_size, void* d_ws, size_t ws_size,
                              hipStream_t stream)
{
    const float* x     = (const float*)d_in[0];
    const float* A     = (const float*)d_in[1];
    const float* Wx    = (const float*)d_in[2];
    const float* Wh    = (const float*)d_in[3];
    const float* Wattn = (const float*)d_in[4];
    const float* b     = (const float*)d_in[5];
    float* out = (float*)d_out;
    char* ws = (char*)d_ws;
    dim3 tb(32, 8);

    const size_t SZ_W2T = (size_t)FH_ * K2_ * 2;         // 16.8 MB
    const size_t SZ_WxT = (size_t)FH_ * D_ * 2;          // 8.4 MB
    const size_t SZ_HB  = (size_t)N_ * K2_ * 2;          // 1 MB each
    const size_t SZ_C   = (size_t)N_ * H_ * 4;           // 1 MB
    const size_t SZ_SP  = (size_t)N_ * 128 * 16 * 4;     // 2 MB
    const size_t SZ_BAR = 4096;
    const size_t SZ_XPB = (size_t)T_ * N_ * FH_ * 2;     // 268.4 MB
    const size_t need_pers = SZ_W2T + SZ_WxT + 2 * SZ_HB + SZ_C + SZ_SP + SZ_BAR + SZ_XPB;

    if (ws_size >= need_pers) {
        size_t off = 0;
        __hip_bfloat16* W2T = (__hip_bfloat16*)(ws + off); off += SZ_W2T;
        __hip_bfloat16* WxT = (__hip_bfloat16*)(ws + off); off += SZ_WxT;
        __hip_bfloat16* hb0 = (__hip_bfloat16*)(ws + off); off += SZ_HB;
        __hip_bfloat16* hb1 = (__hip_bfloat16*)(ws + off); off += SZ_HB;
        float* cbuf    = (float*)(ws + off); off += SZ_C;
        float* sp_part = (float*)(ws + off); off += SZ_SP;
        unsigned* bar  = (unsigned*)(ws + off); off += SZ_BAR;
        __hip_bfloat16* xpb = (__hip_bfloat16*)(ws + off);

        transpose_cast<<<dim3(FH_ / 32, H_ / 32), tb, 0, stream>>>(Wh, FH_, W2T, K2_, 0);
        transpose_cast<<<dim3(FH_ / 32, H_ / 32), tb, 0, stream>>>(Wattn, FH_, W2T, K2_, H_);
        transpose_cast<<<dim3(FH_ / 32, D_ / 32), tb, 0, stream>>>(Wx, FH_, WxT, D_, 0);
        gemm_x<1><<<dim3(FH_ / BN, T_ * N_ / BM), 256, 0, stream>>>(x, WxT, (void*)xpb, 0);
        init_pers<<<N_, 256, 0, stream>>>(A, cbuf, hb0, sp_part, bar);
        persist<<<256, 256, 0, stream>>>(W2T, hb0, hb1, xpb, b, A, cbuf, sp_part, out, bar);
        return;
    }

    // ---- fallback: round-3 path ----
    const size_t F_SP = (size_t)N_ * 64 * 16 * 4;
    const size_t F_XPT = (size_t)N_ * FH_ * 4;
    size_t off = 0;
    __hip_bfloat16* W2T = (__hip_bfloat16*)(ws + off); off += SZ_W2T;
    __hip_bfloat16* WxT = (__hip_bfloat16*)(ws + off); off += SZ_WxT;
    __hip_bfloat16* hb0 = (__hip_bfloat16*)(ws + off); off += SZ_HB;
    __hip_bfloat16* hb1 = (__hip_bfloat16*)(ws + off); off += SZ_HB;
    float* cbuf    = (float*)(ws + off); off += SZ_C;
    float* sp_part = (float*)(ws + off); off += F_SP;
    float* xproj   = (float*)(ws + off);
    size_t rem = (ws_size > off) ? (ws_size - off) : 0;
    int Tc = (int)(rem / F_XPT);
    if (Tc > 16) Tc = 16;
    if (Tc < 1) Tc = 1;

    transpose_cast<<<dim3(FH_ / 32, H_ / 32), tb, 0, stream>>>(Wh, FH_, W2T, K2_, 0);
    transpose_cast<<<dim3(FH_ / 32, H_ / 32), tb, 0, stream>>>(Wattn, FH_, W2T, K2_, H_);
    transpose_cast<<<dim3(FH_ / 32, D_ / 32), tb, 0, stream>>>(Wx, FH_, WxT, D_, 0);
    init_fb<<<N_, 256, 0, stream>>>(A, cbuf, hb0);

    __hip_bfloat16* hbp[2] = {hb0, hb1};
    for (int t0 = 0; t0 < T_; t0 += Tc) {
        int tc = (T_ - t0 < Tc) ? (T_ - t0) : Tc;
        dim3 gx(FH_ / BN, tc * N_ / BM);
        gemm_x<0><<<gx, 256, 0, stream>>>(x, WxT, (void*)xproj, t0);
        for (int tl = 0; tl < tc; tl++) {
            int t = t0 + tl;
            if (t > 0)
                wattn<<<N_, 256, 0, stream>>>(sp_part, A, hbp[t & 1]);
            gemmgates<<<dim3(64, 4), 256, 0, stream>>>(
                hbp[t & 1], hbp[(t + 1) & 1], W2T,
                xproj + (size_t)tl * N_ * FH_, b, A, cbuf, sp_part, out, t);
        }
    }
}

// Round 5
// 10467.424 us; speedup vs baseline: 1.1389x; 1.1389x over previous
//
#include <hip/hip_runtime.h>
#include <hip/hip_bf16.h>
#include <stdint.h>

#define N_ 256
#define T_ 128
#define D_ 1024
#define H_ 1024
#define FH_ 4096
#define K2_ 2048

typedef __bf16 bf16x8 __attribute__((ext_vector_type(8)));
typedef float f32x4 __attribute__((ext_vector_type(4)));

// ---------------- transpose + cast fp32 -> bf16 ----------------
__global__ __launch_bounds__(256) void transpose_cast(
    const float* __restrict__ src, int cols,
    __hip_bfloat16* __restrict__ dst, int dst_stride, int dst_coloff)
{
    __shared__ float tile[32][33];
    int cb = blockIdx.x * 32, rb = blockIdx.y * 32;
    int tx = threadIdx.x, ty = threadIdx.y;  // (32, 8)
#pragma unroll
    for (int i = 0; i < 4; i++)
        tile[ty + i * 8][tx] = src[(size_t)(rb + ty + i * 8) * cols + cb + tx];
    __syncthreads();
#pragma unroll
    for (int i = 0; i < 4; i++)
        dst[(size_t)(cb + ty + i * 8) * dst_stride + dst_coloff + rb + tx] =
            __float2bfloat16(tile[tx][ty + i * 8]);
}

// ---------------- xproj GEMM: C[g][j] = sum_k x[g][k] * WxT[j][k] ----------
#define BM 64
#define BN 128
#define BK 64
#define BKP 72

template <int OUTBF>
__global__ __launch_bounds__(256) void gemm_x(
    const float* __restrict__ Xf,
    const __hip_bfloat16* __restrict__ BT,
    void* __restrict__ Cp, int t0)
{
    __shared__ __hip_bfloat16 Al[BM][BKP];
    __shared__ __hip_bfloat16 Bl[BN][BKP];
    const int tid = threadIdx.x;
    const int lane = tid & 63, wid = tid >> 6;
    const int m0 = blockIdx.y * BM, n0 = blockIdx.x * BN;
    const int wm = (wid >> 1) * 32, wn = (wid & 1) * 64;
    const int rs = tid >> 3, kc = (tid & 7) * 8;
    f32x4 acc[2][4] = {};

    for (int k0 = 0; k0 < D_; k0 += BK) {
#pragma unroll
        for (int p = 0; p < BM; p += 32) {
            int r = rs + p;
            int g = m0 + r;
            int nn = g & 255, tl = g >> 8;
            const float* s = Xf + ((size_t)nn * T_ + (t0 + tl)) * D_ + k0 + kc;
            float4 v0 = *reinterpret_cast<const float4*>(s);
            float4 v1 = *reinterpret_cast<const float4*>(s + 4);
            __hip_bfloat16 h8[8];
            h8[0] = __float2bfloat16(v0.x); h8[1] = __float2bfloat16(v0.y);
            h8[2] = __float2bfloat16(v0.z); h8[3] = __float2bfloat16(v0.w);
            h8[4] = __float2bfloat16(v1.x); h8[5] = __float2bfloat16(v1.y);
            h8[6] = __float2bfloat16(v1.z); h8[7] = __float2bfloat16(v1.w);
            *reinterpret_cast<int4*>(&Al[r][kc]) = *reinterpret_cast<const int4*>(h8);
        }
#pragma unroll
        for (int p = 0; p < BN; p += 32) {
            int r = rs + p;
            const __hip_bfloat16* s = BT + (size_t)(n0 + r) * D_ + k0 + kc;
            *reinterpret_cast<int4*>(&Bl[r][kc]) = *reinterpret_cast<const int4*>(s);
        }
        __syncthreads();
        const int ko = (lane >> 4) * 8;
#pragma unroll
        for (int kk = 0; kk < BK; kk += 32) {
            bf16x8 a0 = *reinterpret_cast<const bf16x8*>(&Al[wm + (lane & 15)][kk + ko]);
            bf16x8 a1 = *reinterpret_cast<const bf16x8*>(&Al[wm + 16 + (lane & 15)][kk + ko]);
#pragma unroll
            for (int ni = 0; ni < 4; ni++) {
                bf16x8 bq = *reinterpret_cast<const bf16x8*>(&Bl[wn + ni * 16 + (lane & 15)][kk + ko]);
                acc[0][ni] = __builtin_amdgcn_mfma_f32_16x16x32_bf16(a0, bq, acc[0][ni], 0, 0, 0);
                acc[1][ni] = __builtin_amdgcn_mfma_f32_16x16x32_bf16(a1, bq, acc[1][ni], 0, 0, 0);
            }
        }
        __syncthreads();
    }
    const int cr = (lane >> 4) * 4, ccol = lane & 15;
#pragma unroll
    for (int mi = 0; mi < 2; mi++)
#pragma unroll
        for (int ni = 0; ni < 4; ni++)
#pragma unroll
            for (int r = 0; r < 4; r++) {
                size_t idx = (size_t)(m0 + wm + mi * 16 + cr + r) * FH_ + (n0 + wn + ni * 16 + ccol);
                if constexpr (OUTBF) {
                    ((__hip_bfloat16*)Cp)[idx] = __float2bfloat16(acc[mi][ni][r]);
                } else {
                    ((float*)Cp)[idx] = acc[mi][ni][r];
                }
            }
}

// ---------------- AW precompute: AW[n][j][l] = sum_h A[n,h,l]*Wattn[h,j] ---
__global__ __launch_bounds__(256) void aw_gemm(
    const float* __restrict__ A, const __hip_bfloat16* __restrict__ WaT,
    __hip_bfloat16* __restrict__ AW)
{
    __shared__ __hip_bfloat16 Al[16][72];
    __shared__ __hip_bfloat16 Bl[128][72];
    const int tid = threadIdx.x, lane = tid & 63, wv = tid >> 6;
    const int n = blockIdx.y, j0 = blockIdx.x * 128;
    const int rs = tid >> 3, kc = (tid & 7) * 8;
    f32x4 acc[2] = {};
    for (int k0 = 0; k0 < 1024; k0 += 64) {
        {
            int h = tid >> 2, lq = (tid & 3) * 4;
            float4 v = *reinterpret_cast<const float4*>(A + ((size_t)n * 1024 + k0 + h) * 16 + lq);
            Al[lq + 0][h] = __float2bfloat16(v.x);
            Al[lq + 1][h] = __float2bfloat16(v.y);
            Al[lq + 2][h] = __float2bfloat16(v.z);
            Al[lq + 3][h] = __float2bfloat16(v.w);
        }
#pragma unroll
        for (int p = 0; p < 128; p += 32) {
            int r = rs + p;
            *reinterpret_cast<int4*>(&Bl[r][kc]) =
                *reinterpret_cast<const int4*>(WaT + (size_t)(j0 + r) * 1024 + k0 + kc);
        }
        __syncthreads();
        const int ko = (lane >> 4) * 8;
#pragma unroll
        for (int kk = 0; kk < 64; kk += 32) {
            bf16x8 a0 = *reinterpret_cast<const bf16x8*>(&Al[lane & 15][kk + ko]);
#pragma unroll
            for (int nf = 0; nf < 2; nf++) {
                bf16x8 bq = *reinterpret_cast<const bf16x8*>(&Bl[wv * 32 + nf * 16 + (lane & 15)][kk + ko]);
                acc[nf] = __builtin_amdgcn_mfma_f32_16x16x32_bf16(a0, bq, acc[nf], 0, 0, 0);
            }
        }
        __syncthreads();
    }
    const int cr = (lane >> 4) * 4, cc = lane & 15;
#pragma unroll
    for (int nf = 0; nf < 2; nf++) {
        __hip_bfloat16 t4[4];
#pragma unroll
        for (int r = 0; r < 4; r++) t4[r] = __float2bfloat16(acc[nf][r]);
        *reinterpret_cast<uint2*>(AW + ((size_t)n * 4096 + j0 + wv * 32 + nf * 16 + cc) * 16 + cr) =
            *reinterpret_cast<uint2*>(t4);
    }
}

// ---------------- A -> bf16 cast ----------------
__global__ __launch_bounds__(256) void abf_cast(
    const float* __restrict__ A, __hip_bfloat16* __restrict__ Abf)
{
    size_t i = ((size_t)blockIdx.x * 256 + threadIdx.x) * 4;
    float4 v = *reinterpret_cast<const float4*>(A + i);
    __hip_bfloat16 o[4];
    o[0] = __float2bfloat16(v.x); o[1] = __float2bfloat16(v.y);
    o[2] = __float2bfloat16(v.z); o[3] = __float2bfloat16(v.w);
    *reinterpret_cast<uint2*>(Abf + i) = *reinterpret_cast<uint2*>(o);
}

// ---------------- init for persistent path ----------------
__global__ __launch_bounds__(256) void init_p(
    const float* __restrict__ A, float* __restrict__ cbuf,
    __hip_bfloat16* __restrict__ hb0, float* __restrict__ scores,
    unsigned* __restrict__ bar)
{
    __shared__ float red[4][16];
    const int n = blockIdx.x, tid = threadIdx.x;
    const int lane = tid & 63, wvv = tid >> 6;
    if (n == 0) { bar[tid] = 0u; bar[256 + tid] = 0u; }
    float a[4][16];
    float hv[4];
#pragma unroll
    for (int q = 0; q < 4; q++) {
        const float4* Ap = reinterpret_cast<const float4*>(A + ((size_t)n * H_ + tid * 4 + q) * 16);
        float4 q0 = Ap[0], q1 = Ap[1], q2 = Ap[2], q3 = Ap[3];
        a[q][0] = q0.x; a[q][1] = q0.y; a[q][2] = q0.z; a[q][3] = q0.w;
        a[q][4] = q1.x; a[q][5] = q1.y; a[q][6] = q1.z; a[q][7] = q1.w;
        a[q][8] = q2.x; a[q][9] = q2.y; a[q][10] = q2.z; a[q][11] = q2.w;
        a[q][12] = q3.x; a[q][13] = q3.y; a[q][14] = q3.z; a[q][15] = q3.w;
        float s = 0.f;
#pragma unroll
        for (int l = 0; l < 16; l++) s += a[q][l];
        hv[q] = s * 0.0625f;
    }
    *reinterpret_cast<float4*>(cbuf + (size_t)n * H_ + tid * 4) = *reinterpret_cast<float4*>(hv);
    __hip_bfloat16 h4[4];
#pragma unroll
    for (int q = 0; q < 4; q++) h4[q] = __float2bfloat16(hv[q]);
    *reinterpret_cast<uint2*>(hb0 + (size_t)n * H_ + tid * 4) = *reinterpret_cast<uint2*>(h4);
    float spv[16];
#pragma unroll
    for (int l = 0; l < 16; l++)
        spv[l] = hv[0] * a[0][l] + hv[1] * a[1][l] + hv[2] * a[2][l] + hv[3] * a[3][l];
#pragma unroll
    for (int l = 0; l < 16; l++) {
        spv[l] += __shfl_xor(spv[l], 1);  spv[l] += __shfl_xor(spv[l], 2);
        spv[l] += __shfl_xor(spv[l], 4);  spv[l] += __shfl_xor(spv[l], 8);
        spv[l] += __shfl_xor(spv[l], 16); spv[l] += __shfl_xor(spv[l], 32);
    }
    if (lane == 0) {
#pragma unroll
        for (int l = 0; l < 16; l++) red[wvv][l] = spv[l];
    }
    __syncthreads();
    if (tid < 16) {
        scores[n * 16 + tid] = red[0][tid] + red[1][tid] + red[2][tid] + red[3][tid];
        scores[4096 + n * 16 + tid] = 0.f;
    }
}

// ---------------- 2-level grid barrier (256 WGs, 8 leaves x 32) -----------
__device__ __forceinline__ void gridbar(unsigned* bar, int g)
{
    __syncthreads();
    if (threadIdx.x == 0) {
        __threadfence();
        unsigned* leaf = bar + (g & 7) * 32;
        unsigned* root = bar + 8 * 32;
        unsigned* gen  = bar + 8 * 32 + 32;
        unsigned tl = __hip_atomic_fetch_add(leaf, 1u, __ATOMIC_ACQ_REL, __HIP_MEMORY_SCOPE_AGENT);
        unsigned r = tl >> 5;
        if ((tl & 31u) == 31u) {
            unsigned tr = __hip_atomic_fetch_add(root, 1u, __ATOMIC_ACQ_REL, __HIP_MEMORY_SCOPE_AGENT);
            if ((tr & 7u) == 7u)
                __hip_atomic_store(gen, r + 1u, __ATOMIC_RELEASE, __HIP_MEMORY_SCOPE_AGENT);
        }
        while (__hip_atomic_load(gen, __ATOMIC_ACQUIRE, __HIP_MEMORY_SCOPE_AGENT) < r + 1u)
            __builtin_amdgcn_s_sleep(1);
        __threadfence();
    }
    __syncthreads();
}

// ---------------- persistent kernel v2: Wh in VGPRs, A-tile in LDS --------
// 256 WGs x 256 thr. WG: jt (16 hidden cols, XCD-major) x mt (64 n rows).
// Wave wv = gate section; its 16 weight cols (16x1024) live in 128 VGPRs.
#define PAD_ROW 1032  // 1024 + 8 bf16 pad -> conflict-free ds_read_b128

__global__ __launch_bounds__(256, 1) void persist2(
    const __hip_bfloat16* __restrict__ WhT,
    __hip_bfloat16* __restrict__ hbA,
    __hip_bfloat16* __restrict__ hbB,
    const __hip_bfloat16* __restrict__ xpb,
    const float* __restrict__ bias,
    const __hip_bfloat16* __restrict__ Abf,
    const __hip_bfloat16* __restrict__ AW2,
    float* __restrict__ cbuf,
    float* __restrict__ scores,   // [3][256][16]
    float* __restrict__ out,
    unsigned* __restrict__ bar,
    int t0, int t1)
{
    __shared__ __align__(16) char smem[149504];
    __hip_bfloat16* As = (__hip_bfloat16*)smem;           // [64][1032]
    float* pls = (float*)(smem + 132096);                  // [64][68]

    const int tid = threadIdx.x;
    const int g = blockIdx.x;
    const int jt = ((g & 7) << 3) | ((g >> 3) & 7);        // XCD-major column strips
    const int mt = g >> 6;
    const int hc0 = jt * 16, n0 = mt * 64;
    const int lane = tid & 63, wv = tid >> 6;
    const int l15 = lane & 15, ko8 = (lane >> 4) * 8;

    // ---- weight fragments into VGPRs (once per launch) ----
    bf16x8 wfrag[32];
    {
        const __hip_bfloat16* wsrc = WhT + ((size_t)(wv * 1024 + hc0 + l15)) * 1024 + ko8;
#pragma unroll
        for (int ks = 0; ks < 32; ks++)
            wfrag[ks] = *reinterpret_cast<const bf16x8*>(wsrc + ks * 32);
    }

    // epilogue-constant state
    const int n_l = tid >> 2, hcq = (tid & 3) * 4;
    const int nn = n0 + n_l;
    float cv[4];
    *reinterpret_cast<float4*>(cv) =
        *reinterpret_cast<const float4*>(cbuf + (size_t)nn * H_ + hc0 + hcq);
    float bv[4][4];
#pragma unroll
    for (int s = 0; s < 4; s++)
        *reinterpret_cast<float4*>(bv[s]) =
            *reinterpret_cast<const float4*>(bias + s * 1024 + hc0 + hcq);

    for (int t = t0; t < t1; ++t) {
        const int p = t & 1;
        const __hip_bfloat16* hbin = p ? hbB : hbA;
        __hip_bfloat16* hbout      = p ? hbA : hbB;
        const float* sc_cur = scores + (size_t)(t % 3) * 4096;
        float* sc_nxt = scores + (size_t)((t + 1) % 3) * 4096;
        float* sc_z   = scores + (size_t)((t + 2) % 3) * 4096;

        // ---- stage A-tile (64 rows x 1024 h, padded) ----
#pragma unroll
        for (int r = 0; r < 16; r++) {
            const int row = wv * 16 + r;
            const __hip_bfloat16* src = hbin + (size_t)(n0 + row) * H_ + lane * 8;
            int4 v0 = *reinterpret_cast<const int4*>(src);
            int4 v1 = *reinterpret_cast<const int4*>(src + 512);
            *reinterpret_cast<int4*>(As + (size_t)row * PAD_ROW + lane * 8) = v0;
            *reinterpret_cast<int4*>(As + (size_t)row * PAD_ROW + 512 + lane * 8) = v1;
        }
        // zero the t+2 scores slot for this WG's n (=g)
        if (tid < 16) sc_z[g * 16 + tid] = 0.f;
        // per-thread softmax weights for row nn (reads fp32 raw scores)
        float w[16];
        {
            const float* srow = sc_cur + nn * 16;
            float4 f0 = *reinterpret_cast<const float4*>(srow);
            float4 f1 = *reinterpret_cast<const float4*>(srow + 4);
            float4 f2 = *reinterpret_cast<const float4*>(srow + 8);
            float4 f3 = *reinterpret_cast<const float4*>(srow + 12);
            float sv[16] = {f0.x, f0.y, f0.z, f0.w, f1.x, f1.y, f1.z, f1.w,
                            f2.x, f2.y, f2.z, f2.w, f3.x, f3.y, f3.z, f3.w};
            float m = sv[0];
#pragma unroll
            for (int l = 1; l < 16; l++) m = fmaxf(m, sv[l]);
            float se = 0.f;
#pragma unroll
            for (int l = 0; l < 16; l++) { w[l] = __expf((sv[l] - m) * 0.03125f); se += w[l]; }
            float inv = 1.f / se;
#pragma unroll
            for (int l = 0; l < 16; l++) w[l] *= inv;
        }
        __syncthreads();

        // ---- MFMA burst: A from LDS, B from VGPRs ----
        f32x4 acc0{}, acc1{}, acc2{}, acc3{};
        {
            const __hip_bfloat16* arow = As + (size_t)l15 * PAD_ROW + ko8;
#pragma unroll
            for (int ks = 0; ks < 32; ks++) {
                bf16x8 a0 = *reinterpret_cast<const bf16x8*>(arow + ks * 32);
                bf16x8 a1 = *reinterpret_cast<const bf16x8*>(arow + 16 * PAD_ROW + ks * 32);
                bf16x8 a2 = *reinterpret_cast<const bf16x8*>(arow + 32 * PAD_ROW + ks * 32);
                bf16x8 a3 = *reinterpret_cast<const bf16x8*>(arow + 48 * PAD_ROW + ks * 32);
                acc0 = __builtin_amdgcn_mfma_f32_16x16x32_bf16(a0, wfrag[ks], acc0, 0, 0, 0);
                acc1 = __builtin_amdgcn_mfma_f32_16x16x32_bf16(a1, wfrag[ks], acc1, 0, 0, 0);
                acc2 = __builtin_amdgcn_mfma_f32_16x16x32_bf16(a2, wfrag[ks], acc2, 0, 0, 0);
                acc3 = __builtin_amdgcn_mfma_f32_16x16x32_bf16(a3, wfrag[ks], acc3, 0, 0, 0);
            }
        }
        __syncthreads();  // all waves done reading As before pls (aliased region is separate, but keep order strict)
        {
            const int cr = (lane >> 4) * 4;
#pragma unroll
            for (int r = 0; r < 4; r++) {
                pls[(0 * 16 + cr + r) * 68 + wv * 16 + l15] = acc0[r];
                pls[(1 * 16 + cr + r) * 68 + wv * 16 + l15] = acc1[r];
                pls[(2 * 16 + cr + r) * 68 + wv * 16 + l15] = acc2[r];
                pls[(3 * 16 + cr + r) * 68 + wv * 16 + l15] = acc3[r];
            }
        }
        __syncthreads();

        // ---- epilogue: pre = pls + xp + b + AW-sum; gates; outputs; scores ----
        {
            const float* plr = pls + n_l * 68;
            const __hip_bfloat16* xrow = xpb + ((size_t)(t - t0) * N_ + nn) * FH_ + hc0 + hcq;
            float pre[4][4];
#pragma unroll
            for (int s = 0; s < 4; s++) {
                __hip_bfloat16 xb[4];
                *reinterpret_cast<uint2*>(xb) = *reinterpret_cast<const uint2*>(xrow + s * 1024);
                const __hip_bfloat16* awp = AW2 + ((size_t)nn * FH_ + s * 1024 + hc0 + hcq) * 16;
#pragma unroll
                for (int q = 0; q < 4; q++) {
                    bf16x8 a0 = *reinterpret_cast<const bf16x8*>(awp + q * 16);
                    bf16x8 a1 = *reinterpret_cast<const bf16x8*>(awp + q * 16 + 8);
                    float aw = 0.f;
#pragma unroll
                    for (int l = 0; l < 8; l++) aw += w[l] * (float)a0[l];
#pragma unroll
                    for (int l = 0; l < 8; l++) aw += w[l + 8] * (float)a1[l];
                    pre[s][q] = plr[s * 16 + hcq + q] + __bfloat162float(xb[q]) + bv[s][q] + aw;
                }
            }
            float hq[4];
#pragma unroll
            for (int q = 0; q < 4; q++) {
                float iv = 1.f / (1.f + __expf(-pre[0][q]));
                float fv = 1.f / (1.f + __expf(-pre[1][q]));
                float ov = 1.f / (1.f + __expf(-pre[2][q]));
                float gx = fminf(fmaxf(pre[3][q], -20.f), 20.f);
                float eg = __expf(2.f * gx);
                float gv = (eg - 1.f) / (eg + 1.f);
                float c2 = fv * cv[q] + iv * gv;
                cv[q] = c2;
                float cx = fminf(fmaxf(c2, -20.f), 20.f);
                float ec = __expf(2.f * cx);
                hq[q] = ov * (ec - 1.f) / (ec + 1.f);
            }
            *reinterpret_cast<float4*>(out + ((size_t)nn * T_ + t) * H_ + hc0 + hcq) =
                *reinterpret_cast<float4*>(hq);
            __hip_bfloat16 h4[4];
#pragma unroll
            for (int q = 0; q < 4; q++) h4[q] = __float2bfloat16(hq[q]);
            *reinterpret_cast<uint2*>(hbout + (size_t)nn * H_ + hc0 + hcq) =
                *reinterpret_cast<uint2*>(h4);

            float spv[16];
#pragma unroll
            for (int l = 0; l < 16; l++) spv[l] = 0.f;
#pragma unroll
            for (int q = 0; q < 4; q++) {
                const __hip_bfloat16* ap = Abf + ((size_t)nn * H_ + hc0 + hcq + q) * 16;
                bf16x8 a0 = *reinterpret_cast<const bf16x8*>(ap);
                bf16x8 a1 = *reinterpret_cast<const bf16x8*>(ap + 8);
                float h = hq[q];
#pragma unroll
                for (int l = 0; l < 8; l++) { spv[l] += h * (float)a0[l]; spv[l + 8] += h * (float)a1[l]; }
            }
#pragma unroll
            for (int l = 0; l < 16; l++) {
                spv[l] += __shfl_xor(spv[l], 1);
                spv[l] += __shfl_xor(spv[l], 2);
            }
            if ((tid & 3) == 0) {
#pragma unroll
                for (int l = 0; l < 16; l++)
                    atomicAdd(sc_nxt + nn * 16 + l, spv[l]);
            }
        }
        gridbar(bar, g);
    }
    // carry c across chunk launches
    *reinterpret_cast<float4*>(cbuf + (size_t)nn * H_ + hc0 + hcq) =
        *reinterpret_cast<float4*>(cv);
}

// ================= fallback (round-3) kernels =================
__global__ __launch_bounds__(256) void init_fb(
    const float* __restrict__ A, float* __restrict__ cbuf,
    __hip_bfloat16* __restrict__ hb)
{
    __shared__ float red[4][16];
    __shared__ float wl[16];
    const int n = blockIdx.x, tid = threadIdx.x;
    const int lane = tid & 63, wv = tid >> 6;
    const int h0i = tid * 4;
    float a[4][16];
    float hv[4];
#pragma unroll
    for (int q = 0; q < 4; q++) {
        const float4* Ap = reinterpret_cast<const float4*>(A + ((size_t)n * H_ + h0i + q) * 16);
        float4 q0 = Ap[0], q1 = Ap[1], q2 = Ap[2], q3 = Ap[3];
        a[q][0] = q0.x; a[q][1] = q0.y; a[q][2] = q0.z; a[q][3] = q0.w;
        a[q][4] = q1.x; a[q][5] = q1.y; a[q][6] = q1.z; a[q][7] = q1.w;
        a[q][8] = q2.x; a[q][9] = q2.y; a[q][10] = q2.z; a[q][11] = q2.w;
        a[q][12] = q3.x; a[q][13] = q3.y; a[q][14] = q3.z; a[q][15] = q3.w;
        float s = 0.f;
#pragma unroll
        for (int l = 0; l < 16; l++) s += a[q][l];
        hv[q] = s * 0.0625f;
    }
    *reinterpret_cast<float4*>(cbuf + (size_t)n * H_ + h0i) = *reinterpret_cast<float4*>(hv);
    {
        __hip_bfloat16 h4[4];
#pragma unroll
        for (int q = 0; q < 4; q++) h4[q] = __float2bfloat16(hv[q]);
        *reinterpret_cast<uint2*>(hb + (size_t)n * K2_ + h0i) = *reinterpret_cast<uint2*>(h4);
    }
    float sp[16];
#pragma unroll
    for (int l = 0; l < 16; l++) {
        sp[l] = hv[0] * a[0][l] + hv[1] * a[1][l] + hv[2] * a[2][l] + hv[3] * a[3][l];
#pragma unroll
        for (int off = 1; off < 64; off <<= 1) sp[l] += __shfl_xor(sp[l], off);
    }
    if (lane == 0) {
#pragma unroll
        for (int l = 0; l < 16; l++) red[wv][l] = sp[l];
    }
    __syncthreads();
    if (tid < 16) {
        float s = (red[0][tid] + red[1][tid] + red[2][tid] + red[3][tid]) * 0.03125f;
        float m = s;
        m = fmaxf(m, __shfl_xor(m, 8)); m = fmaxf(m, __shfl_xor(m, 4));
        m = fmaxf(m, __shfl_xor(m, 2)); m = fmaxf(m, __shfl_xor(m, 1));
        float e = __expf(s - m);
        float se = e;
        se += __shfl_xor(se, 8); se += __shfl_xor(se, 4);
        se += __shfl_xor(se, 2); se += __shfl_xor(se, 1);
        wl[tid] = e / se;
    }
    __syncthreads();
    float w[16];
#pragma unroll
    for (int l = 0; l < 16; l++) w[l] = wl[l];
    __hip_bfloat16 at4[4];
#pragma unroll
    for (int q = 0; q < 4; q++) {
        float s = 0.f;
#pragma unroll
        for (int l = 0; l < 16; l++) s += w[l] * a[q][l];
        at4[q] = __float2bfloat16(s);
    }
    *reinterpret_cast<uint2*>(hb + (size_t)n * K2_ + H_ + h0i) = *reinterpret_cast<uint2*>(at4);
}

__global__ __launch_bounds__(256) void wattn(
    const float* __restrict__ sp_part, const float* __restrict__ A,
    __hip_bfloat16* __restrict__ hb)
{
    __shared__ float red[4][16];
    __shared__ float wl[16];
    const int n = blockIdx.x, tid = threadIdx.x;
    if (tid < 64) {
        const int g = tid >> 4, l = tid & 15;
        float s = 0.f;
        const float* sp = sp_part + ((size_t)n * 64 + g * 16) * 16 + l;
#pragma unroll
        for (int j = 0; j < 16; j++) s += sp[j * 16];
        red[g][l] = s;
    }
    __syncthreads();
    if (tid < 16) {
        float s = (red[0][tid] + red[1][tid] + red[2][tid] + red[3][tid]) * 0.03125f;
        float m = s;
        m = fmaxf(m, __shfl_xor(m, 8)); m = fmaxf(m, __shfl_xor(m, 4));
        m = fmaxf(m, __shfl_xor(m, 2)); m = fmaxf(m, __shfl_xor(m, 1));
        float e = __expf(s - m);
        float se = e;
        se += __shfl_xor(se, 8); se += __shfl_xor(se, 4);
        se += __shfl_xor(se, 2); se += __shfl_xor(se, 1);
        wl[tid] = e / se;
    }
    __syncthreads();
    float w[16];
#pragma unroll
    for (int l = 0; l < 16; l++) w[l] = wl[l];
    const int h0i = tid * 4;
    __hip_bfloat16 at4[4];
#pragma unroll
    for (int q = 0; q < 4; q++) {
        const float4* Ap = reinterpret_cast<const float4*>(A + ((size_t)n * H_ + h0i + q) * 16);
        float4 q0 = Ap[0], q1 = Ap[1], q2 = Ap[2], q3 = Ap[3];
        float s = w[0] * q0.x + w[1] * q0.y + w[2] * q0.z + w[3] * q0.w
                + w[4] * q1.x + w[5] * q1.y + w[6] * q1.z + w[7] * q1.w
                + w[8] * q2.x + w[9] * q2.y + w[10] * q2.z + w[11] * q2.w
                + w[12] * q3.x + w[13] * q3.y + w[14] * q3.z + w[15] * q3.w;
        at4[q] = __float2bfloat16(s);
    }
    *reinterpret_cast<uint2*>(hb + (size_t)n * K2_ + H_ + h0i) = *reinterpret_cast<uint2*>(at4);
}

__global__ __launch_bounds__(256) void gemmgates(
    const __hip_bfloat16* __restrict__ hb_in,
    __hip_bfloat16* __restrict__ hb_out,
    const __hip_bfloat16* __restrict__ W2T,
    const float* __restrict__ xp,
    const float* __restrict__ bias,
    const float* __restrict__ Afp,
    float* __restrict__ cbuf,
    float* __restrict__ sp_part,
    float* __restrict__ out, int t)
{
    __shared__ __hip_bfloat16 Al[64][72];
    __shared__ __hip_bfloat16 Bl[64][72];
    __shared__ float pls[64][68];
    const int tid = threadIdx.x;
    const int lane = tid & 63, wv = tid >> 6;
    const int jt = blockIdx.x, mt = blockIdx.y;
    const int hc0 = jt * 16, n0 = mt * 64;
    const int rs = tid >> 3, kc = (tid & 7) * 8;
    const int wm = (wv >> 1) * 32, wn = (wv & 1) * 32;
    f32x4 acc[2][2] = {};

    for (int k0 = 0; k0 < K2_; k0 += 64) {
#pragma unroll
        for (int p = 0; p < 64; p += 32) {
            int r = rs + p;
            *reinterpret_cast<int4*>(&Al[r][kc]) =
                *reinterpret_cast<const int4*>(hb_in + (size_t)(n0 + r) * K2_ + k0 + kc);
            int grow = (r >> 4) * 1024 + hc0 + (r & 15);
            *reinterpret_cast<int4*>(&Bl[r][kc]) =
                *reinterpret_cast<const int4*>(W2T + (size_t)grow * K2_ + k0 + kc);
        }
        __syncthreads();
        const int ko = (lane >> 4) * 8;
#pragma unroll
        for (int kk = 0; kk < 64; kk += 32) {
            bf16x8 a0 = *reinterpret_cast<const bf16x8*>(&Al[wm + (lane & 15)][kk + ko]);
            bf16x8 a1 = *reinterpret_cast<const bf16x8*>(&Al[wm + 16 + (lane & 15)][kk + ko]);
            bf16x8 b0 = *reinterpret_cast<const bf16x8*>(&Bl[wn + (lane & 15)][kk + ko]);
            bf16x8 b1 = *reinterpret_cast<const bf16x8*>(&Bl[wn + 16 + (lane & 15)][kk + ko]);
            acc[0][0] = __builtin_amdgcn_mfma_f32_16x16x32_bf16(a0, b0, acc[0][0], 0, 0, 0);
            acc[0][1] = __builtin_amdgcn_mfma_f32_16x16x32_bf16(a0, b1, acc[0][1], 0, 0, 0);
            acc[1][0] = __builtin_amdgcn_mfma_f32_16x16x32_bf16(a1, b0, acc[1][0], 0, 0, 0);
            acc[1][1] = __builtin_amdgcn_mfma_f32_16x16x32_bf16(a1, b1, acc[1][1], 0, 0, 0);
        }
        __syncthreads();
    }
    {
        const int cr = (lane >> 4) * 4, cc = lane & 15;
#pragma unroll
        for (int mf = 0; mf < 2; mf++)
#pragma unroll
            for (int nf = 0; nf < 2; nf++)
#pragma unroll
                for (int r = 0; r < 4; r++)
                    pls[wm + mf * 16 + cr + r][wn + nf * 16 + cc] = acc[mf][nf][r];
    }
    __syncthreads();
    {
        const int n_l = tid >> 2, hcq = (tid & 3) * 4;
        const int nn = n0 + n_l;
        float pre_[4][4];
#pragma unroll
        for (int s = 0; s < 4; s++) {
            const int gj = s * 1024 + hc0 + hcq;
            float4 xv = *reinterpret_cast<const float4*>(xp + (size_t)nn * FH_ + gj);
            float4 bvv = *reinterpret_cast<const float4*>(bias + gj);
            float4 pv = *reinterpret_cast<const float4*>(&pls[n_l][s * 16 + hcq]);
            pre_[s][0] = pv.x + xv.x + bvv.x;
            pre_[s][1] = pv.y + xv.y + bvv.y;
            pre_[s][2] = pv.z + xv.z + bvv.z;
            pre_[s][3] = pv.w + xv.w + bvv.w;
        }
        float cvv[4];
        *reinterpret_cast<float4*>(cvv) =
            *reinterpret_cast<const float4*>(cbuf + (size_t)nn * H_ + hc0 + hcq);
        float hq[4];
#pragma unroll
        for (int q = 0; q < 4; q++) {
            float iv = 1.f / (1.f + __expf(-pre_[0][q]));
            float fv = 1.f / (1.f + __expf(-pre_[1][q]));
            float ov = 1.f / (1.f + __expf(-pre_[2][q]));
            float gx = fminf(fmaxf(pre_[3][q], -20.f), 20.f);
            float eg = __expf(2.f * gx);
            float gv = (eg - 1.f) / (eg + 1.f);
            float cc2 = fv * cvv[q] + iv * gv;
            cvv[q] = cc2;
            float cx = fminf(fmaxf(cc2, -20.f), 20.f);
            float ec = __expf(2.f * cx);
            hq[q] = ov * (ec - 1.f) / (ec + 1.f);
        }
        *reinterpret_cast<float4*>(cbuf + (size_t)nn * H_ + hc0 + hcq) =
            *reinterpret_cast<float4*>(cvv);
        *reinterpret_cast<float4*>(out + ((size_t)nn * T_ + t) * H_ + hc0 + hcq) =
            *reinterpret_cast<float4*>(hq);
        __hip_bfloat16 h4[4];
#pragma unroll
        for (int q = 0; q < 4; q++) h4[q] = __float2bfloat16(hq[q]);
        *reinterpret_cast<uint2*>(hb_out + (size_t)nn * K2_ + hc0 + hcq) =
            *reinterpret_cast<uint2*>(h4);

        float spv[16];
#pragma unroll
        for (int l = 0; l < 16; l++) spv[l] = 0.f;
#pragma unroll
        for (int q = 0; q < 4; q++) {
            const float* ar = Afp + ((size_t)nn * H_ + hc0 + hcq + q) * 16;
            float4 a0 = *reinterpret_cast<const float4*>(ar);
            float4 a1 = *reinterpret_cast<const float4*>(ar + 4);
            float4 a2 = *reinterpret_cast<const float4*>(ar + 8);
            float4 a3 = *reinterpret_cast<const float4*>(ar + 12);
            spv[0] += hq[q] * a0.x; spv[1] += hq[q] * a0.y;
            spv[2] += hq[q] * a0.z; spv[3] += hq[q] * a0.w;
            spv[4] += hq[q] * a1.x; spv[5] += hq[q] * a1.y;
            spv[6] += hq[q] * a1.z; spv[7] += hq[q] * a1.w;
            spv[8] += hq[q] * a2.x; spv[9] += hq[q] * a2.y;
            spv[10] += hq[q] * a2.z; spv[11] += hq[q] * a2.w;
            spv[12] += hq[q] * a3.x; spv[13] += hq[q] * a3.y;
            spv[14] += hq[q] * a3.z; spv[15] += hq[q] * a3.w;
        }
#pragma unroll
        for (int l = 0; l < 16; l++) {
            spv[l] += __shfl_xor(spv[l], 1);
            spv[l] += __shfl_xor(spv[l], 2);
        }
        if ((tid & 3) == 0) {
            float* d = sp_part + ((size_t)nn * 64 + jt) * 16;
            *reinterpret_cast<float4*>(d)      = *reinterpret_cast<float4*>(&spv[0]);
            *reinterpret_cast<float4*>(d + 4)  = *reinterpret_cast<float4*>(&spv[4]);
            *reinterpret_cast<float4*>(d + 8)  = *reinterpret_cast<float4*>(&spv[8]);
            *reinterpret_cast<float4*>(d + 12) = *reinterpret_cast<float4*>(&spv[12]);
        }
    }
}

extern "C" void kernel_launch(void* const* d_in, const int* in_sizes, int n_in,
                              void* d_out, int out_size, void* d_ws, size_t ws_size,
                              hipStream_t stream)
{
    const float* x     = (const float*)d_in[0];
    const float* A     = (const float*)d_in[1];
    const float* Wx    = (const float*)d_in[2];
    const float* Wh    = (const float*)d_in[3];
    const float* Wattn = (const float*)d_in[4];
    const float* b     = (const float*)d_in[5];
    float* out = (float*)d_out;
    char* ws = (char*)d_ws;
    dim3 tb(32, 8);

    // ---- persistent-v2 workspace ----
    const size_t SZ_WhT = (size_t)FH_ * H_ * 2;          // 8.4 MB (Wh^T)
    const size_t SZ_WxT = (size_t)FH_ * D_ * 2;          // 8.4 MB
    const size_t SZ_AW  = (size_t)N_ * FH_ * 16 * 2;     // 33.5 MB
    const size_t SZ_Abf = (size_t)N_ * H_ * 16 * 2;      // 8.4 MB
    const size_t SZ_HB  = (size_t)N_ * H_ * 2;           // 512 KB (x2)
    const size_t SZ_C   = (size_t)N_ * H_ * 4;           // 1 MB
    const size_t SZ_SC  = 3 * 4096 * 4;                  // 48 KB
    const size_t SZ_BAR = 4096;
    const int    TC     = 32;
    const size_t SZ_XPC = (size_t)TC * N_ * FH_ * 2;     // 67 MB
    const size_t need = SZ_WhT + SZ_WxT + SZ_AW + SZ_Abf + 2 * SZ_HB + SZ_C +
                        SZ_SC + SZ_BAR + SZ_XPC;         // ~128 MB

    if (ws_size >= need) {
        size_t off = 0;
        __hip_bfloat16* WhT = (__hip_bfloat16*)(ws + off); off += SZ_WhT;
        __hip_bfloat16* WxT = (__hip_bfloat16*)(ws + off); off += SZ_WxT;
        __hip_bfloat16* AW2 = (__hip_bfloat16*)(ws + off); off += SZ_AW;
        __hip_bfloat16* Abf = (__hip_bfloat16*)(ws + off); off += SZ_Abf;
        __hip_bfloat16* hbA = (__hip_bfloat16*)(ws + off); off += SZ_HB;
        __hip_bfloat16* hbB = (__hip_bfloat16*)(ws + off); off += SZ_HB;
        float* cbuf   = (float*)(ws + off); off += SZ_C;
        float* scores = (float*)(ws + off); off += SZ_SC;
        unsigned* bar = (unsigned*)(ws + off); off += SZ_BAR;
        __hip_bfloat16* xpc = (__hip_bfloat16*)(ws + off);
        __hip_bfloat16* WaT = xpc;  // aliased: used only before first gemm_x

        transpose_cast<<<dim3(FH_ / 32, H_ / 32), tb, 0, stream>>>(Wh, FH_, WhT, H_, 0);
        transpose_cast<<<dim3(FH_ / 32, H_ / 32), tb, 0, stream>>>(Wattn, FH_, WaT, H_, 0);
        aw_gemm<<<dim3(32, N_), 256, 0, stream>>>(A, WaT, AW2);
        transpose_cast<<<dim3(FH_ / 32, D_ / 32), tb, 0, stream>>>(Wx, FH_, WxT, D_, 0);
        abf_cast<<<dim3(4096), 256, 0, stream>>>(A, Abf);
        init_p<<<N_, 256, 0, stream>>>(A, cbuf, hbA, scores, bar);

        for (int t0 = 0; t0 < T_; t0 += TC) {
            gemm_x<1><<<dim3(FH_ / BN, TC * N_ / BM), 256, 0, stream>>>(x, WxT, (void*)xpc, t0);
            persist2<<<256, 256, 0, stream>>>(WhT, hbA, hbB, xpc, b, Abf, AW2,
                                              cbuf, scores, out, bar, t0, t0 + TC);
        }
        return;
    }

    // ---- fallback: round-3 path ----
    const size_t SZ_W2T = (size_t)FH_ * K2_ * 2;
    const size_t SZ_HB2 = (size_t)N_ * K2_ * 2;
    const size_t F_SP = (size_t)N_ * 64 * 16 * 4;
    const size_t F_XPT = (size_t)N_ * FH_ * 4;
    size_t off = 0;
    __hip_bfloat16* W2T = (__hip_bfloat16*)(ws + off); off += SZ_W2T;
    __hip_bfloat16* WxT = (__hip_bfloat16*)(ws + off); off += SZ_WxT;
    __hip_bfloat16* hb0 = (__hip_bfloat16*)(ws + off); off += SZ_HB2;
    __hip_bfloat16* hb1 = (__hip_bfloat16*)(ws + off); off += SZ_HB2;
    float* cbuf    = (float*)(ws + off); off += SZ_C;
    float* sp_part = (float*)(ws + off); off += F_SP;
    float* xproj   = (float*)(ws + off);
    size_t rem = (ws_size > off) ? (ws_size - off) : 0;
    int Tc = (int)(rem / F_XPT);
    if (Tc > 16) Tc = 16;
    if (Tc < 1) Tc = 1;

    transpose_cast<<<dim3(FH_ / 32, H_ / 32), tb, 0, stream>>>(Wh, FH_, W2T, K2_, 0);
    transpose_cast<<<dim3(FH_ / 32, H_ / 32), tb, 0, stream>>>(Wattn, FH_, W2T, K2_, H_);
    transpose_cast<<<dim3(FH_ / 32, D_ / 32), tb, 0, stream>>>(Wx, FH_, WxT, D_, 0);
    init_fb<<<N_, 256, 0, stream>>>(A, cbuf, hb0);

    __hip_bfloat16* hbp[2] = {hb0, hb1};
    for (int t0 = 0; t0 < T_; t0 += Tc) {
        int tc = (T_ - t0 < Tc) ? (T_ - t0) : Tc;
        dim3 gx(FH_ / BN, tc * N_ / BM);
        gemm_x<0><<<gx, 256, 0, stream>>>(x, WxT, (void*)xproj, t0);
        for (int tl = 0; tl < tc; tl++) {
            int t = t0 + tl;
            if (t > 0)
                wattn<<<N_, 256, 0, stream>>>(sp_part, A, hbp[t & 1]);
            gemmgates<<<dim3(64, 4), 256, 0, stream>>>(
                hbp[t & 1], hbp[(t + 1) & 1], W2T,
                xproj + (size_t)tl * N_ * FH_, b, A, cbuf, sp_part, out, t);
        }
    }
}

// Round 6
// 9217.719 us; speedup vs baseline: 1.2933x; 1.1356x over previous
//
#include <hip/hip_runtime.h>
#include <hip/hip_bf16.h>
#include <stdint.h>

#define N_ 256
#define T_ 128
#define D_ 1024
#define H_ 1024
#define FH_ 4096
#define K2_ 2048

typedef __bf16 bf16x8 __attribute__((ext_vector_type(8)));
typedef float f32x4 __attribute__((ext_vector_type(4)));

// ---------------- transpose + cast fp32 -> bf16 ----------------
// dst[c][dst_coloff + r] = (bf16) src[r][c]
__global__ __launch_bounds__(256) void transpose_cast(
    const float* __restrict__ src, int cols,
    __hip_bfloat16* __restrict__ dst, int dst_stride, int dst_coloff)
{
    __shared__ float tile[32][33];
    int cb = blockIdx.x * 32, rb = blockIdx.y * 32;
    int tx = threadIdx.x, ty = threadIdx.y;  // (32, 8)
#pragma unroll
    for (int i = 0; i < 4; i++)
        tile[ty + i * 8][tx] = src[(size_t)(rb + ty + i * 8) * cols + cb + tx];
    __syncthreads();
#pragma unroll
    for (int i = 0; i < 4; i++)
        dst[(size_t)(cb + ty + i * 8) * dst_stride + dst_coloff + rb + tx] =
            __float2bfloat16(tile[tx][ty + i * 8]);
}

// ---------------- xproj GEMM: xpb[tl][n][j] = x[n][t0+tl] @ Wx ----------
#define BM 64
#define BN 128
#define BK 64
#define BKP 72

__global__ __launch_bounds__(256) void gemm_x(
    const float* __restrict__ Xf,
    const __hip_bfloat16* __restrict__ BT,
    __hip_bfloat16* __restrict__ Cp, int t0)
{
    __shared__ __hip_bfloat16 Al[BM][BKP];
    __shared__ __hip_bfloat16 Bl[BN][BKP];
    const int tid = threadIdx.x;
    const int lane = tid & 63, wid = tid >> 6;
    const int m0 = blockIdx.y * BM, n0 = blockIdx.x * BN;
    const int wm = (wid >> 1) * 32, wn = (wid & 1) * 64;
    const int rs = tid >> 3, kc = (tid & 7) * 8;
    f32x4 acc[2][4] = {};

    for (int k0 = 0; k0 < D_; k0 += BK) {
#pragma unroll
        for (int p = 0; p < BM; p += 32) {
            int r = rs + p;
            int g = m0 + r;
            int nn = g & 255, tl = g >> 8;
            const float* s = Xf + ((size_t)nn * T_ + (t0 + tl)) * D_ + k0 + kc;
            float4 v0 = *reinterpret_cast<const float4*>(s);
            float4 v1 = *reinterpret_cast<const float4*>(s + 4);
            __hip_bfloat16 h8[8];
            h8[0] = __float2bfloat16(v0.x); h8[1] = __float2bfloat16(v0.y);
            h8[2] = __float2bfloat16(v0.z); h8[3] = __float2bfloat16(v0.w);
            h8[4] = __float2bfloat16(v1.x); h8[5] = __float2bfloat16(v1.y);
            h8[6] = __float2bfloat16(v1.z); h8[7] = __float2bfloat16(v1.w);
            *reinterpret_cast<int4*>(&Al[r][kc]) = *reinterpret_cast<const int4*>(h8);
        }
#pragma unroll
        for (int p = 0; p < BN; p += 32) {
            int r = rs + p;
            const __hip_bfloat16* s = BT + (size_t)(n0 + r) * D_ + k0 + kc;
            *reinterpret_cast<int4*>(&Bl[r][kc]) = *reinterpret_cast<const int4*>(s);
        }
        __syncthreads();
        const int ko = (lane >> 4) * 8;
#pragma unroll
        for (int kk = 0; kk < BK; kk += 32) {
            bf16x8 a0 = *reinterpret_cast<const bf16x8*>(&Al[wm + (lane & 15)][kk + ko]);
            bf16x8 a1 = *reinterpret_cast<const bf16x8*>(&Al[wm + 16 + (lane & 15)][kk + ko]);
#pragma unroll
            for (int ni = 0; ni < 4; ni++) {
                bf16x8 bq = *reinterpret_cast<const bf16x8*>(&Bl[wn + ni * 16 + (lane & 15)][kk + ko]);
                acc[0][ni] = __builtin_amdgcn_mfma_f32_16x16x32_bf16(a0, bq, acc[0][ni], 0, 0, 0);
                acc[1][ni] = __builtin_amdgcn_mfma_f32_16x16x32_bf16(a1, bq, acc[1][ni], 0, 0, 0);
            }
        }
        __syncthreads();
    }
    const int cr = (lane >> 4) * 4, ccol = lane & 15;
#pragma unroll
    for (int mi = 0; mi < 2; mi++)
#pragma unroll
        for (int ni = 0; ni < 4; ni++)
#pragma unroll
            for (int r = 0; r < 4; r++) {
                size_t idx = (size_t)(m0 + wm + mi * 16 + cr + r) * FH_ + (n0 + wn + ni * 16 + ccol);
                Cp[idx] = __float2bfloat16(acc[mi][ni][r]);
            }
}

// ---------------- A -> bf16 cast (layout preserved [n][1024][16]) ---------
__global__ __launch_bounds__(256) void abf_cast(
    const float* __restrict__ A, __hip_bfloat16* __restrict__ Abf)
{
    size_t i = ((size_t)blockIdx.x * 256 + threadIdx.x) * 4;
    float4 v = *reinterpret_cast<const float4*>(A + i);
    __hip_bfloat16 o[4];
    o[0] = __float2bfloat16(v.x); o[1] = __float2bfloat16(v.y);
    o[2] = __float2bfloat16(v.z); o[3] = __float2bfloat16(v.w);
    *reinterpret_cast<uint2*>(Abf + i) = *reinterpret_cast<uint2*>(o);
}

// ---------------- init: h0, c0, hb h-half, raw scores slot0 ----------------
__global__ __launch_bounds__(256) void init_p(
    const float* __restrict__ A, float* __restrict__ cbuf,
    __hip_bfloat16* __restrict__ hb0, float* __restrict__ scores)
{
    __shared__ float red[4][16];
    const int n = blockIdx.x, tid = threadIdx.x;
    const int lane = tid & 63, wvv = tid >> 6;
    float a[4][16];
    float hv[4];
#pragma unroll
    for (int q = 0; q < 4; q++) {
        const float4* Ap = reinterpret_cast<const float4*>(A + ((size_t)n * H_ + tid * 4 + q) * 16);
        float4 q0 = Ap[0], q1 = Ap[1], q2 = Ap[2], q3 = Ap[3];
        a[q][0] = q0.x; a[q][1] = q0.y; a[q][2] = q0.z; a[q][3] = q0.w;
        a[q][4] = q1.x; a[q][5] = q1.y; a[q][6] = q1.z; a[q][7] = q1.w;
        a[q][8] = q2.x; a[q][9] = q2.y; a[q][10] = q2.z; a[q][11] = q2.w;
        a[q][12] = q3.x; a[q][13] = q3.y; a[q][14] = q3.z; a[q][15] = q3.w;
        float s = 0.f;
#pragma unroll
        for (int l = 0; l < 16; l++) s += a[q][l];
        hv[q] = s * 0.0625f;
    }
    *reinterpret_cast<float4*>(cbuf + (size_t)n * H_ + tid * 4) = *reinterpret_cast<float4*>(hv);
    __hip_bfloat16 h4[4];
#pragma unroll
    for (int q = 0; q < 4; q++) h4[q] = __float2bfloat16(hv[q]);
    *reinterpret_cast<uint2*>(hb0 + (size_t)n * K2_ + tid * 4) = *reinterpret_cast<uint2*>(h4);
    float spv[16];
#pragma unroll
    for (int l = 0; l < 16; l++)
        spv[l] = hv[0] * a[0][l] + hv[1] * a[1][l] + hv[2] * a[2][l] + hv[3] * a[3][l];
#pragma unroll
    for (int l = 0; l < 16; l++) {
        spv[l] += __shfl_xor(spv[l], 1);  spv[l] += __shfl_xor(spv[l], 2);
        spv[l] += __shfl_xor(spv[l], 4);  spv[l] += __shfl_xor(spv[l], 8);
        spv[l] += __shfl_xor(spv[l], 16); spv[l] += __shfl_xor(spv[l], 32);
    }
    if (lane == 0) {
#pragma unroll
        for (int l = 0; l < 16; l++) red[wvv][l] = spv[l];
    }
    __syncthreads();
    if (tid < 16)
        scores[n * 16 + tid] = red[0][tid] + red[1][tid] + red[2][tid] + red[3][tid];
}

// ---------------- wattn2: softmax(scores) -> attn half of hb --------------
// one n per WG; also zeroes next score slot for this n.
__global__ __launch_bounds__(256) void wattn2(
    const float* __restrict__ scores_r, float* __restrict__ scores_z,
    const __hip_bfloat16* __restrict__ Abf, __hip_bfloat16* __restrict__ hbt)
{
    const int n = blockIdx.x, tid = threadIdx.x;
    if (tid < 16) scores_z[n * 16 + tid] = 0.f;
    const float* sr = scores_r + n * 16;
    float4 f0 = *reinterpret_cast<const float4*>(sr);
    float4 f1 = *reinterpret_cast<const float4*>(sr + 4);
    float4 f2 = *reinterpret_cast<const float4*>(sr + 8);
    float4 f3 = *reinterpret_cast<const float4*>(sr + 12);
    float sv[16] = {f0.x, f0.y, f0.z, f0.w, f1.x, f1.y, f1.z, f1.w,
                    f2.x, f2.y, f2.z, f2.w, f3.x, f3.y, f3.z, f3.w};
    float m = sv[0];
#pragma unroll
    for (int l = 1; l < 16; l++) m = fmaxf(m, sv[l]);
    float w[16], se = 0.f;
#pragma unroll
    for (int l = 0; l < 16; l++) { w[l] = __expf((sv[l] - m) * 0.03125f); se += w[l]; }
    float inv = 1.f / se;
#pragma unroll
    for (int l = 0; l < 16; l++) w[l] *= inv;
    const __hip_bfloat16* ap = Abf + ((size_t)n * H_ + tid * 4) * 16;
    __hip_bfloat16 o4[4];
#pragma unroll
    for (int q = 0; q < 4; q++) {
        bf16x8 a0 = *reinterpret_cast<const bf16x8*>(ap + q * 16);
        bf16x8 a1 = *reinterpret_cast<const bf16x8*>(ap + q * 16 + 8);
        float s = 0.f;
#pragma unroll
        for (int l = 0; l < 8; l++) s += w[l] * (float)a0[l];
#pragma unroll
        for (int l = 0; l < 8; l++) s += w[l + 8] * (float)a1[l];
        o4[q] = __float2bfloat16(s);
    }
    *reinterpret_cast<uint2*>(hbt + (size_t)n * K2_ + H_ + tid * 4) =
        *reinterpret_cast<uint2*>(o4);
}

// ---------------- step GEMM + gates (1024 threads, 16 waves) --------------
// grid (jt=64, mt=4). WG: 64 n-rows x 16 hidden cols x 4 sections, K=2048.
// Wave = one 16x16 output tile. BK=128, 2-barrier loop.
__global__ __launch_bounds__(1024) void step_gemm(
    const __hip_bfloat16* __restrict__ hb_in,
    __hip_bfloat16* __restrict__ hb_out,
    const __hip_bfloat16* __restrict__ W2T,
    const __hip_bfloat16* __restrict__ xp,   // [256][4096] bf16, this t
    const float* __restrict__ bias,
    const __hip_bfloat16* __restrict__ Abf,
    float* __restrict__ cbuf,
    float* __restrict__ sc_add,
    float* __restrict__ out, int t)
{
    __shared__ __hip_bfloat16 Al[64][136];
    __shared__ __hip_bfloat16 Bl[64][136];
    __shared__ float pls[64][68];
    const int tid = threadIdx.x;
    const int lane = tid & 63, wv = tid >> 6;
    const int jt = blockIdx.x, mt = blockIdx.y;
    const int hc0 = jt * 16, n0 = mt * 64;
    const int rs = tid >> 4, kc = (tid & 15) * 8;
    const int grow = (rs >> 4) * 1024 + hc0 + (rs & 15);
    const int wm = (wv >> 2) * 16, wn = (wv & 3) * 16;
    const int l15 = lane & 15, ko8 = (lane >> 4) * 8;
    f32x4 acc{};
    const __hip_bfloat16* asrc = hb_in + (size_t)(n0 + rs) * K2_ + kc;
    const __hip_bfloat16* bsrc = W2T + (size_t)grow * K2_ + kc;

    for (int k0 = 0; k0 < K2_; k0 += 128) {
        *reinterpret_cast<int4*>(&Al[rs][kc]) = *reinterpret_cast<const int4*>(asrc + k0);
        *reinterpret_cast<int4*>(&Bl[rs][kc]) = *reinterpret_cast<const int4*>(bsrc + k0);
        __syncthreads();
#pragma unroll
        for (int kf = 0; kf < 4; kf++) {
            bf16x8 af = *reinterpret_cast<const bf16x8*>(&Al[wm + l15][kf * 32 + ko8]);
            bf16x8 bq = *reinterpret_cast<const bf16x8*>(&Bl[wn + l15][kf * 32 + ko8]);
            acc = __builtin_amdgcn_mfma_f32_16x16x32_bf16(af, bq, acc, 0, 0, 0);
        }
        __syncthreads();
    }
    {
        const int cr = (lane >> 4) * 4;
#pragma unroll
        for (int r = 0; r < 4; r++)
            pls[wm + cr + r][wn + l15] = acc[r];
    }
    __syncthreads();

    // ---- epilogue: thread -> (n_l = tid>>4, col c = tid&15) ----
    {
        const int n_l = tid >> 4, c = tid & 15;
        const int nn = n0 + n_l;
        float pre[4];
#pragma unroll
        for (int s = 0; s < 4; s++) {
            const int gj = s * 1024 + hc0 + c;
            pre[s] = pls[n_l][s * 16 + c]
                   + __bfloat162float(xp[(size_t)nn * FH_ + gj])
                   + bias[gj];
        }
        float iv = 1.f / (1.f + __expf(-pre[0]));
        float fv = 1.f / (1.f + __expf(-pre[1]));
        float ov = 1.f / (1.f + __expf(-pre[2]));
        float gx = fminf(fmaxf(pre[3], -20.f), 20.f);
        float eg = __expf(2.f * gx);
        float gv = (eg - 1.f) / (eg + 1.f);
        const size_t ci = (size_t)nn * H_ + hc0 + c;
        float c2 = fv * cbuf[ci] + iv * gv;
        cbuf[ci] = c2;
        float cx = fminf(fmaxf(c2, -20.f), 20.f);
        float ec = __expf(2.f * cx);
        float h = ov * (ec - 1.f) / (ec + 1.f);
        out[((size_t)nn * T_ + t) * H_ + hc0 + c] = h;
        hb_out[(size_t)nn * K2_ + hc0 + c] = __float2bfloat16(h);

        // score partials: spv[l] = sum over this WG's 16 cols of h * A[n][col][l]
        const __hip_bfloat16* ap = Abf + ((size_t)nn * H_ + hc0 + c) * 16;
        bf16x8 a0 = *reinterpret_cast<const bf16x8*>(ap);
        bf16x8 a1 = *reinterpret_cast<const bf16x8*>(ap + 8);
        float spv[16];
#pragma unroll
        for (int l = 0; l < 8; l++) { spv[l] = h * (float)a0[l]; spv[l + 8] = h * (float)a1[l]; }
#pragma unroll
        for (int l = 0; l < 16; l++) {
            spv[l] += __shfl_xor(spv[l], 1);
            spv[l] += __shfl_xor(spv[l], 2);
            spv[l] += __shfl_xor(spv[l], 4);
            spv[l] += __shfl_xor(spv[l], 8);
        }
        if (c == 0) {
#pragma unroll
            for (int l = 0; l < 16; l++)
                atomicAdd(sc_add + nn * 16 + l, spv[l]);
        }
    }
}

extern "C" void kernel_launch(void* const* d_in, const int* in_sizes, int n_in,
                              void* d_out, int out_size, void* d_ws, size_t ws_size,
                              hipStream_t stream)
{
    const float* x     = (const float*)d_in[0];
    const float* A     = (const float*)d_in[1];
    const float* Wx    = (const float*)d_in[2];
    const float* Wh    = (const float*)d_in[3];
    const float* Wattn = (const float*)d_in[4];
    const float* b     = (const float*)d_in[5];
    float* out = (float*)d_out;
    char* ws = (char*)d_ws;
    dim3 tb(32, 8);

    const size_t SZ_W2T = (size_t)FH_ * K2_ * 2;       // 16.8 MB  [Wh;Wattn]^T
    const size_t SZ_WxT = (size_t)FH_ * D_ * 2;        // 8.4 MB
    const size_t SZ_Abf = (size_t)N_ * H_ * 16 * 2;    // 8.4 MB
    const size_t SZ_HB  = (size_t)N_ * K2_ * 2;        // 1 MB (x2)
    const size_t SZ_C   = (size_t)N_ * H_ * 4;         // 1 MB
    const size_t SZ_SC  = 3 * (size_t)N_ * 16 * 4;     // 48 KB
    const size_t SZ_XPT = (size_t)N_ * FH_ * 2;        // 2.1 MB per timestep (bf16)

    size_t off = 0;
    __hip_bfloat16* W2T = (__hip_bfloat16*)(ws + off); off += SZ_W2T;
    __hip_bfloat16* WxT = (__hip_bfloat16*)(ws + off); off += SZ_WxT;
    __hip_bfloat16* Abf = (__hip_bfloat16*)(ws + off); off += SZ_Abf;
    __hip_bfloat16* hbA = (__hip_bfloat16*)(ws + off); off += SZ_HB;
    __hip_bfloat16* hbB = (__hip_bfloat16*)(ws + off); off += SZ_HB;
    float* cbuf   = (float*)(ws + off); off += SZ_C;
    float* scores = (float*)(ws + off); off += SZ_SC;
    __hip_bfloat16* xpb = (__hip_bfloat16*)(ws + off);

    // xproj chunk size: largest power-of-two timestep count that fits
    size_t rem = (ws_size > off) ? (ws_size - off) : 0;
    int TC = 64;
    while (TC > 1 && (size_t)TC * SZ_XPT > rem) TC >>= 1;

    // ---- weight prep ----
    transpose_cast<<<dim3(FH_ / 32, H_ / 32), tb, 0, stream>>>(Wh, FH_, W2T, K2_, 0);
    transpose_cast<<<dim3(FH_ / 32, H_ / 32), tb, 0, stream>>>(Wattn, FH_, W2T, K2_, H_);
    transpose_cast<<<dim3(FH_ / 32, D_ / 32), tb, 0, stream>>>(Wx, FH_, WxT, D_, 0);
    abf_cast<<<dim3((N_ * H_ * 16) / 1024), 256, 0, stream>>>(A, Abf);
    init_p<<<N_, 256, 0, stream>>>(A, cbuf, hbA, scores);  // scores slot 0

    __hip_bfloat16* hbp[2] = {hbA, hbB};
    for (int t0 = 0; t0 < T_; t0 += TC) {
        int tc = (T_ - t0 < TC) ? (T_ - t0) : TC;
        gemm_x<<<dim3(FH_ / BN, tc * N_ / BM), 256, 0, stream>>>(x, WxT, xpb, t0);
        for (int tl = 0; tl < tc; tl++) {
            int t = t0 + tl;
            // wattn2: read slot t%3, zero slot (t+1)%3, write attn into hb[t&1]
            wattn2<<<N_, 256, 0, stream>>>(
                scores + (size_t)(t % 3) * N_ * 16,
                scores + (size_t)((t + 1) % 3) * N_ * 16,
                Abf, hbp[t & 1]);
            // step_gemm: GEMM K=2048 + gates; atomics into slot (t+1)%3
            step_gemm<<<dim3(64, 4), 1024, 0, stream>>>(
                hbp[t & 1], hbp[(t + 1) & 1], W2T,
                xpb + (size_t)tl * N_ * FH_, b, Abf, cbuf,
                scores + (size_t)((t + 1) % 3) * N_ * 16,
                out, t);
        }
    }
}

// Round 7
// 3113.369 us; speedup vs baseline: 3.8290x; 2.9607x over previous
//
#include <hip/hip_runtime.h>
#include <hip/hip_bf16.h>
#include <stdint.h>

#define N_ 256
#define T_ 128
#define D_ 1024
#define H_ 1024
#define FH_ 4096
#define K2_ 2048

typedef __bf16 bf16x8 __attribute__((ext_vector_type(8)));
typedef float f32x4 __attribute__((ext_vector_type(4)));

// ---------------- transpose + cast fp32 -> bf16 ----------------
// dst[c][dst_coloff + r] = (bf16) src[r][c]
__global__ __launch_bounds__(256) void transpose_cast(
    const float* __restrict__ src, int cols,
    __hip_bfloat16* __restrict__ dst, int dst_stride, int dst_coloff)
{
    __shared__ float tile[32][33];
    int cb = blockIdx.x * 32, rb = blockIdx.y * 32;
    int tx = threadIdx.x, ty = threadIdx.y;  // (32, 8)
#pragma unroll
    for (int i = 0; i < 4; i++)
        tile[ty + i * 8][tx] = src[(size_t)(rb + ty + i * 8) * cols + cb + tx];
    __syncthreads();
#pragma unroll
    for (int i = 0; i < 4; i++)
        dst[(size_t)(cb + ty + i * 8) * dst_stride + dst_coloff + rb + tx] =
            __float2bfloat16(tile[tx][ty + i * 8]);
}

// ---------------- xproj GEMM: xpb[tl][n][j] = x[n][t0+tl] @ Wx (bf16 out) --
#define BM 64
#define BN 128
#define BK 64
#define BKP 72

__global__ __launch_bounds__(256) void gemm_x(
    const float* __restrict__ Xf,
    const __hip_bfloat16* __restrict__ BT,
    __hip_bfloat16* __restrict__ Cp, int t0)
{
    __shared__ __hip_bfloat16 Al[BM][BKP];
    __shared__ __hip_bfloat16 Bl[BN][BKP];
    const int tid = threadIdx.x;
    const int lane = tid & 63, wid = tid >> 6;
    const int m0 = blockIdx.y * BM, n0 = blockIdx.x * BN;
    const int wm = (wid >> 1) * 32, wn = (wid & 1) * 64;
    const int rs = tid >> 3, kc = (tid & 7) * 8;
    f32x4 acc[2][4] = {};

    for (int k0 = 0; k0 < D_; k0 += BK) {
#pragma unroll
        for (int p = 0; p < BM; p += 32) {
            int r = rs + p;
            int g = m0 + r;
            int nn = g & 255, tl = g >> 8;
            const float* s = Xf + ((size_t)nn * T_ + (t0 + tl)) * D_ + k0 + kc;
            float4 v0 = *reinterpret_cast<const float4*>(s);
            float4 v1 = *reinterpret_cast<const float4*>(s + 4);
            __hip_bfloat16 h8[8];
            h8[0] = __float2bfloat16(v0.x); h8[1] = __float2bfloat16(v0.y);
            h8[2] = __float2bfloat16(v0.z); h8[3] = __float2bfloat16(v0.w);
            h8[4] = __float2bfloat16(v1.x); h8[5] = __float2bfloat16(v1.y);
            h8[6] = __float2bfloat16(v1.z); h8[7] = __float2bfloat16(v1.w);
            *reinterpret_cast<int4*>(&Al[r][kc]) = *reinterpret_cast<const int4*>(h8);
        }
#pragma unroll
        for (int p = 0; p < BN; p += 32) {
            int r = rs + p;
            const __hip_bfloat16* s = BT + (size_t)(n0 + r) * D_ + k0 + kc;
            *reinterpret_cast<int4*>(&Bl[r][kc]) = *reinterpret_cast<const int4*>(s);
        }
        __syncthreads();
        const int ko = (lane >> 4) * 8;
#pragma unroll
        for (int kk = 0; kk < BK; kk += 32) {
            bf16x8 a0 = *reinterpret_cast<const bf16x8*>(&Al[wm + (lane & 15)][kk + ko]);
            bf16x8 a1 = *reinterpret_cast<const bf16x8*>(&Al[wm + 16 + (lane & 15)][kk + ko]);
#pragma unroll
            for (int ni = 0; ni < 4; ni++) {
                bf16x8 bq = *reinterpret_cast<const bf16x8*>(&Bl[wn + ni * 16 + (lane & 15)][kk + ko]);
                acc[0][ni] = __builtin_amdgcn_mfma_f32_16x16x32_bf16(a0, bq, acc[0][ni], 0, 0, 0);
                acc[1][ni] = __builtin_amdgcn_mfma_f32_16x16x32_bf16(a1, bq, acc[1][ni], 0, 0, 0);
            }
        }
        __syncthreads();
    }
    const int cr = (lane >> 4) * 4, ccol = lane & 15;
#pragma unroll
    for (int mi = 0; mi < 2; mi++)
#pragma unroll
        for (int ni = 0; ni < 4; ni++)
#pragma unroll
            for (int r = 0; r < 4; r++) {
                size_t idx = (size_t)(m0 + wm + mi * 16 + cr + r) * FH_ + (n0 + wn + ni * 16 + ccol);
                Cp[idx] = __float2bfloat16(acc[mi][ni][r]);
            }
}

// ---------------- A -> bf16 cast (layout preserved [n][1024][16]) ---------
__global__ __launch_bounds__(256) void abf_cast(
    const float* __restrict__ A, __hip_bfloat16* __restrict__ Abf)
{
    size_t i = ((size_t)blockIdx.x * 256 + threadIdx.x) * 4;
    float4 v = *reinterpret_cast<const float4*>(A + i);
    __hip_bfloat16 o[4];
    o[0] = __float2bfloat16(v.x); o[1] = __float2bfloat16(v.y);
    o[2] = __float2bfloat16(v.z); o[3] = __float2bfloat16(v.w);
    *reinterpret_cast<uint2*>(Abf + i) = *reinterpret_cast<uint2*>(o);
}

// ---------------- init: h0 + c0 only ----------------
__global__ __launch_bounds__(256) void init_p(
    const float* __restrict__ A, float* __restrict__ cbuf,
    __hip_bfloat16* __restrict__ hb0)
{
    const int n = blockIdx.x, tid = threadIdx.x;
    float hv[4];
#pragma unroll
    for (int q = 0; q < 4; q++) {
        const float4* Ap = reinterpret_cast<const float4*>(A + ((size_t)n * H_ + tid * 4 + q) * 16);
        float4 q0 = Ap[0], q1 = Ap[1], q2 = Ap[2], q3 = Ap[3];
        float s = q0.x + q0.y + q0.z + q0.w + q1.x + q1.y + q1.z + q1.w
                + q2.x + q2.y + q2.z + q2.w + q3.x + q3.y + q3.z + q3.w;
        hv[q] = s * 0.0625f;
    }
    *reinterpret_cast<float4*>(cbuf + (size_t)n * H_ + tid * 4) = *reinterpret_cast<float4*>(hv);
    __hip_bfloat16 h4[4];
#pragma unroll
    for (int q = 0; q < 4; q++) h4[q] = __float2bfloat16(hv[q]);
    *reinterpret_cast<uint2*>(hb0 + (size_t)n * K2_ + tid * 4) = *reinterpret_cast<uint2*>(h4);
}

// ---------------- wattn2: scores + softmax + attn, one n per WG ----------
// Reads h-half of hbt (written by prev step), writes attn-half of hbt.
__global__ __launch_bounds__(256) void wattn2(
    __hip_bfloat16* __restrict__ hbt,
    const __hip_bfloat16* __restrict__ Abf)
{
    __shared__ float red[4][16];
    const int n = blockIdx.x, tid = threadIdx.x;
    const int lane = tid & 63, wv4 = tid >> 6;

    // 4 h values for this thread's 4 hidden indices
    float h4[4];
    {
        uint2 hraw = *reinterpret_cast<const uint2*>(hbt + (size_t)n * K2_ + tid * 4);
        __hip_bfloat16 hb4[4];
        *reinterpret_cast<uint2*>(hb4) = hraw;
#pragma unroll
        for (int q = 0; q < 4; q++) h4[q] = __bfloat162float(hb4[q]);
    }
    // A[n][tid*4+q][l], l=0..15
    bf16x8 a[4][2];
    const __hip_bfloat16* ap = Abf + ((size_t)n * H_ + tid * 4) * 16;
#pragma unroll
    for (int q = 0; q < 4; q++) {
        a[q][0] = *reinterpret_cast<const bf16x8*>(ap + q * 16);
        a[q][1] = *reinterpret_cast<const bf16x8*>(ap + q * 16 + 8);
    }
    float spv[16];
#pragma unroll
    for (int l = 0; l < 8; l++) {
        spv[l]     = h4[0] * (float)a[0][0][l] + h4[1] * (float)a[1][0][l]
                   + h4[2] * (float)a[2][0][l] + h4[3] * (float)a[3][0][l];
        spv[l + 8] = h4[0] * (float)a[0][1][l] + h4[1] * (float)a[1][1][l]
                   + h4[2] * (float)a[2][1][l] + h4[3] * (float)a[3][1][l];
    }
#pragma unroll
    for (int l = 0; l < 16; l++) {
        spv[l] += __shfl_xor(spv[l], 1);  spv[l] += __shfl_xor(spv[l], 2);
        spv[l] += __shfl_xor(spv[l], 4);  spv[l] += __shfl_xor(spv[l], 8);
        spv[l] += __shfl_xor(spv[l], 16); spv[l] += __shfl_xor(spv[l], 32);
    }
    if (lane == 0) {
#pragma unroll
        for (int l = 0; l < 16; l++) red[wv4][l] = spv[l];
    }
    __syncthreads();
    float w[16], se = 0.f;
    {
        float sc[16], m;
#pragma unroll
        for (int l = 0; l < 16; l++)
            sc[l] = (red[0][l] + red[1][l] + red[2][l] + red[3][l]) * 0.03125f;
        m = sc[0];
#pragma unroll
        for (int l = 1; l < 16; l++) m = fmaxf(m, sc[l]);
#pragma unroll
        for (int l = 0; l < 16; l++) { w[l] = __expf(sc[l] - m); se += w[l]; }
        float inv = 1.f / se;
#pragma unroll
        for (int l = 0; l < 16; l++) w[l] *= inv;
    }
    __hip_bfloat16 o4[4];
#pragma unroll
    for (int q = 0; q < 4; q++) {
        float s = 0.f;
#pragma unroll
        for (int l = 0; l < 8; l++) s += w[l] * (float)a[q][0][l];
#pragma unroll
        for (int l = 0; l < 8; l++) s += w[l + 8] * (float)a[q][1][l];
        o4[q] = __float2bfloat16(s);
    }
    *reinterpret_cast<uint2*>(hbt + (size_t)n * K2_ + H_ + tid * 4) =
        *reinterpret_cast<uint2*>(o4);
}

// ---------------- step GEMM + gates, XCD-clustered ----------------
// 256 WGs x 512 thr. bid = xcd + 8*q; ct = (bid&7) + 8*(q>>2) in 0..63 (16
// hidden cols x 4 sections each); r = q&3 (64 n-rows). All WGs sharing a W2T
// slice sit on one XCD -> W2T slice stays L2-resident across steps.
// K = 2048, BK = 128, double-buffered LDS with register prefetch.
#define LDAp 136

__global__ __launch_bounds__(512) void step_gemm(
    const __hip_bfloat16* __restrict__ hb_in,
    __hip_bfloat16* __restrict__ hb_out,
    const __hip_bfloat16* __restrict__ W2T,
    const __hip_bfloat16* __restrict__ xp,   // [256][4096] bf16, this t
    const float* __restrict__ bias,
    float* __restrict__ cbuf,
    float* __restrict__ out, int t)
{
    __shared__ __align__(16) char smem[69632];
    float* pls = (float*)smem;  // [64][68] fp32, aliases buffer Al0 after loop

    const int tid = threadIdx.x;
    const int lane = tid & 63, wv = tid >> 6;
    const int bid = blockIdx.x;
    const int q = bid >> 3;
    const int ct = (bid & 7) + 8 * (q >> 2);   // 0..63, XCD = ct%8
    const int r  = q & 3;                      // 0..3
    const int hc0 = ct * 16, n0 = r * 64;
    const int rs = tid >> 4;                   // 0..31
    const int kc = (tid & 15) * 8;
    const int l15 = lane & 15, ko8 = (lane >> 4) * 8;
    const int wm = (wv >> 1) * 16, wn = (wv & 1) * 32;

    const int gB0 = ((rs) >> 4) * 1024 + hc0 + (rs & 15);
    const int gB1 = ((rs + 32) >> 4) * 1024 + hc0 + ((rs + 32) & 15);
    const __hip_bfloat16* aS0 = hb_in + (size_t)(n0 + rs) * K2_ + kc;
    const __hip_bfloat16* aS1 = hb_in + (size_t)(n0 + rs + 32) * K2_ + kc;
    const __hip_bfloat16* bS0 = W2T + (size_t)gB0 * K2_ + kc;
    const __hip_bfloat16* bS1 = W2T + (size_t)gB1 * K2_ + kc;

    int4 ra0, ra1, rb0, rb1;
    auto LOAD = [&](int k0) {
        ra0 = *reinterpret_cast<const int4*>(aS0 + k0);
        ra1 = *reinterpret_cast<const int4*>(aS1 + k0);
        rb0 = *reinterpret_cast<const int4*>(bS0 + k0);
        rb1 = *reinterpret_cast<const int4*>(bS1 + k0);
    };
    auto WRITE = [&](int b) {
        __hip_bfloat16* Al = (__hip_bfloat16*)(smem + b * 17408);
        __hip_bfloat16* Bl = (__hip_bfloat16*)(smem + 34816 + b * 17408);
        *reinterpret_cast<int4*>(Al + rs * LDAp + kc) = ra0;
        *reinterpret_cast<int4*>(Al + (rs + 32) * LDAp + kc) = ra1;
        *reinterpret_cast<int4*>(Bl + rs * LDAp + kc) = rb0;
        *reinterpret_cast<int4*>(Bl + (rs + 32) * LDAp + kc) = rb1;
    };

    LOAD(0);
    WRITE(0);
    __syncthreads();

    f32x4 acc0{}, acc1{};
#pragma unroll 1
    for (int it = 0; it < 16; ++it) {
        if (it < 15) LOAD((it + 1) * 128);
        const int cur = it & 1;
        const __hip_bfloat16* pA  = (const __hip_bfloat16*)(smem + cur * 17408) + (wm + l15) * LDAp + ko8;
        const __hip_bfloat16* pB0 = (const __hip_bfloat16*)(smem + 34816 + cur * 17408) + (wn + l15) * LDAp + ko8;
        const __hip_bfloat16* pB1 = pB0 + 16 * LDAp;
#pragma unroll
        for (int kf = 0; kf < 4; kf++) {
            bf16x8 af = *reinterpret_cast<const bf16x8*>(pA + kf * 32);
            bf16x8 b0 = *reinterpret_cast<const bf16x8*>(pB0 + kf * 32);
            bf16x8 b1 = *reinterpret_cast<const bf16x8*>(pB1 + kf * 32);
            acc0 = __builtin_amdgcn_mfma_f32_16x16x32_bf16(af, b0, acc0, 0, 0, 0);
            acc1 = __builtin_amdgcn_mfma_f32_16x16x32_bf16(af, b1, acc1, 0, 0, 0);
        }
        __syncthreads();                 // all waves done reading buf[cur]
        if (it < 15) {
            WRITE(cur ^ 1);
            __syncthreads();             // next-buf writes visible
        }
    }

    // pls (aliases Al0; last MFMA used buf1 and was followed by a barrier)
    {
        const int cr = (lane >> 4) * 4;
#pragma unroll
        for (int r4 = 0; r4 < 4; r4++) {
            pls[(wm + cr + r4) * 68 + wn + l15]      = acc0[r4];
            pls[(wm + cr + r4) * 68 + wn + 16 + l15] = acc1[r4];
        }
    }
    __syncthreads();

    // ---- epilogue: thread -> (n_l = tid>>3, 2 cols at (tid&7)*2) ----
    {
        const int n_l = tid >> 3, c2 = (tid & 7) * 2;
        const int nn = n0 + n_l;
        float hv2[2], cv2[2];
        const size_t cbase = (size_t)nn * H_ + hc0 + c2;
        float2 cold = *reinterpret_cast<const float2*>(cbuf + cbase);
        cv2[0] = cold.x; cv2[1] = cold.y;
#pragma unroll
        for (int cc = 0; cc < 2; cc++) {
            const int c = c2 + cc;
            float pre[4];
#pragma unroll
            for (int s = 0; s < 4; s++) {
                const int gj = s * 1024 + hc0 + c;
                pre[s] = pls[n_l * 68 + s * 16 + c]
                       + __bfloat162float(xp[(size_t)nn * FH_ + gj]) + bias[gj];
            }
            float iv = 1.f / (1.f + __expf(-pre[0]));
            float fv = 1.f / (1.f + __expf(-pre[1]));
            float ov = 1.f / (1.f + __expf(-pre[2]));
            float gx = fminf(fmaxf(pre[3], -20.f), 20.f);
            float eg = __expf(2.f * gx);
            float gv = (eg - 1.f) / (eg + 1.f);
            float c2v = fv * cv2[cc] + iv * gv;
            cv2[cc] = c2v;
            float cx = fminf(fmaxf(c2v, -20.f), 20.f);
            float ec = __expf(2.f * cx);
            hv2[cc] = ov * (ec - 1.f) / (ec + 1.f);
        }
        *reinterpret_cast<float2*>(cbuf + cbase) = make_float2(cv2[0], cv2[1]);
        *reinterpret_cast<float2*>(out + ((size_t)nn * T_ + t) * H_ + hc0 + c2) =
            make_float2(hv2[0], hv2[1]);
        __hip_bfloat16 h2[2];
        h2[0] = __float2bfloat16(hv2[0]);
        h2[1] = __float2bfloat16(hv2[1]);
        *reinterpret_cast<uint32_t*>(hb_out + (size_t)nn * K2_ + hc0 + c2) =
            *reinterpret_cast<uint32_t*>(h2);
    }
}

extern "C" void kernel_launch(void* const* d_in, const int* in_sizes, int n_in,
                              void* d_out, int out_size, void* d_ws, size_t ws_size,
                              hipStream_t stream)
{
    const float* x     = (const float*)d_in[0];
    const float* A     = (const float*)d_in[1];
    const float* Wx    = (const float*)d_in[2];
    const float* Wh    = (const float*)d_in[3];
    const float* Wattn = (const float*)d_in[4];
    const float* b     = (const float*)d_in[5];
    float* out = (float*)d_out;
    char* ws = (char*)d_ws;
    dim3 tb(32, 8);

    const size_t SZ_W2T = (size_t)FH_ * K2_ * 2;       // 16.8 MB  [Wh;Wattn]^T
    const size_t SZ_WxT = (size_t)FH_ * D_ * 2;        // 8.4 MB
    const size_t SZ_Abf = (size_t)N_ * H_ * 16 * 2;    // 8.4 MB
    const size_t SZ_HB  = (size_t)N_ * K2_ * 2;        // 1 MB (x2)
    const size_t SZ_C   = (size_t)N_ * H_ * 4;         // 1 MB
    const size_t SZ_XPT = (size_t)N_ * FH_ * 2;        // 2.1 MB per timestep

    size_t off = 0;
    __hip_bfloat16* W2T = (__hip_bfloat16*)(ws + off); off += SZ_W2T;
    __hip_bfloat16* WxT = (__hip_bfloat16*)(ws + off); off += SZ_WxT;
    __hip_bfloat16* Abf = (__hip_bfloat16*)(ws + off); off += SZ_Abf;
    __hip_bfloat16* hbA = (__hip_bfloat16*)(ws + off); off += SZ_HB;
    __hip_bfloat16* hbB = (__hip_bfloat16*)(ws + off); off += SZ_HB;
    float* cbuf = (float*)(ws + off); off += SZ_C;
    __hip_bfloat16* xpb = (__hip_bfloat16*)(ws + off);

    size_t rem = (ws_size > off) ? (ws_size - off) : 0;
    int TC = 64;
    while (TC > 1 && (size_t)TC * SZ_XPT > rem) TC >>= 1;

    // ---- weight / A prep ----
    transpose_cast<<<dim3(FH_ / 32, H_ / 32), tb, 0, stream>>>(Wh, FH_, W2T, K2_, 0);
    transpose_cast<<<dim3(FH_ / 32, H_ / 32), tb, 0, stream>>>(Wattn, FH_, W2T, K2_, H_);
    transpose_cast<<<dim3(FH_ / 32, D_ / 32), tb, 0, stream>>>(Wx, FH_, WxT, D_, 0);
    abf_cast<<<dim3((N_ * H_ * 16) / 1024), 256, 0, stream>>>(A, Abf);
    init_p<<<N_, 256, 0, stream>>>(A, cbuf, hbA);

    __hip_bfloat16* hbp[2] = {hbA, hbB};
    for (int t0 = 0; t0 < T_; t0 += TC) {
        int tc = (T_ - t0 < TC) ? (T_ - t0) : TC;
        gemm_x<<<dim3(FH_ / BN, tc * N_ / BM), 256, 0, stream>>>(x, WxT, xpb, t0);
        for (int tl = 0; tl < tc; tl++) {
            int t = t0 + tl;
            // scores + softmax + attn for step t (fills attn-half of hb[t&1])
            wattn2<<<N_, 256, 0, stream>>>(hbp[t & 1], Abf);
            // GEMM K=2048 + gates; writes h-half of hb[(t+1)&1]
            step_gemm<<<dim3(256), 512, 0, stream>>>(
                hbp[t & 1], hbp[(t + 1) & 1], W2T,
                xpb + (size_t)tl * N_ * FH_, b, cbuf, out, t);
        }
    }
}